// Round 3
// baseline (271.229 us; speedup 1.0000x reference)
//
#include <hip/hip_runtime.h>
#include <hip/hip_bf16.h>
#include <math.h>

// Problem constants
#define NTOK 25088      // 8*56*56
#define NB   8
#define HH   56
#define WW   56
#define CCH  256
#define NGRP 16
#define NPTS 9
#define HIDN 1024

typedef __attribute__((ext_vector_type(8))) __bf16 bf16x8;
typedef __attribute__((ext_vector_type(4))) __bf16 bf16x4;
typedef __attribute__((ext_vector_type(4))) float  f32x4;

static __device__ __forceinline__ void gl_lds16(const void* g, void* l) {
    __builtin_amdgcn_global_load_lds((const __attribute__((address_space(1))) void*)g,
                                     (__attribute__((address_space(3))) void*)l, 16, 0, 0);
}

static __device__ __forceinline__ float gelu_exact(float v) {
    return 0.5f * v * (1.0f + erff(v * 0.70710678118654752f));
}

// ---------------- f32 -> bf16 convert (vectorized x4) ----------------
__global__ __launch_bounds__(256)
void cvt_kernel(const float* __restrict__ s, __bf16* __restrict__ d, int n4) {
    int i = blockIdx.x * 256 + threadIdx.x;
    if (i >= n4) return;
    float4 v = ((const float4*)s)[i];
    bf16x4 o = {(__bf16)v.x, (__bf16)v.y, (__bf16)v.z, (__bf16)v.w};
    ((bf16x4*)d)[i] = o;
}

// ---------------- LayerNorm: one wave per token (C=256) ----------------
__global__ __launch_bounds__(256)
void ln_kernel(const float* __restrict__ x, const float* __restrict__ g,
               const float* __restrict__ b, float* __restrict__ outf,
               __bf16* __restrict__ outb, int ntok) {
    int gid  = blockIdx.x * 256 + threadIdx.x;
    int t    = gid >> 6;
    int lane = threadIdx.x & 63;
    if (t >= ntok) return;
    float4 v = ((const float4*)(x + (size_t)t * CCH))[lane];
    float s = v.x + v.y + v.z + v.w;
#pragma unroll
    for (int o = 1; o < 64; o <<= 1) s += __shfl_xor(s, o);
    float mu = s * 0.00390625f;
    float dx = v.x - mu, dy = v.y - mu, dz = v.z - mu, dw = v.w - mu;
    float q = dx * dx + dy * dy + dz * dz + dw * dw;
#pragma unroll
    for (int o = 1; o < 64; o <<= 1) q += __shfl_xor(q, o);
    float rstd = rsqrtf(q * 0.00390625f + 1e-6f);
    float4 gg = ((const float4*)g)[lane];
    float4 bb = ((const float4*)b)[lane];
    float ox = dx * rstd * gg.x + bb.x;
    float oy = dy * rstd * gg.y + bb.y;
    float oz = dz * rstd * gg.z + bb.z;
    float ow = dw * rstd * gg.w + bb.w;
    if (outf) ((float4*)(outf + (size_t)t * CCH))[lane] = make_float4(ox, oy, oz, ow);
    bf16x4 ob = {(__bf16)ox, (__bf16)oy, (__bf16)oz, (__bf16)ow};
    ((bf16x4*)(outb + (size_t)t * CCH))[lane] = ob;
}

// ---------------- depthwise 3x3 conv (pad 1), thread = token x 4 channels ----------------
__global__ __launch_bounds__(256)
void dwconv_kernel(const float* __restrict__ ln, const float* __restrict__ wt,
                   const float* __restrict__ bias, __bf16* __restrict__ out) {
    int gid = blockIdx.x * 256 + threadIdx.x;
    int t = gid >> 6;
    int cq = gid & 63;
    if (t >= NTOK) return;
    int n = t / (HH * WW), hw = t % (HH * WW);
    int h = hw / WW, w0 = hw % WW;
    float4 a = ((const float4*)bias)[cq];
    const float4* l4 = (const float4*)ln;
    const float4* w4 = (const float4*)wt;
#pragma unroll
    for (int ky = 0; ky < 3; ++ky) {
        int y = h + ky - 1;
        if (y < 0 || y >= HH) continue;
#pragma unroll
        for (int kx = 0; kx < 3; ++kx) {
            int x = w0 + kx - 1;
            if (x < 0 || x >= WW) continue;
            float4 v = l4[(size_t)(n * HH * WW + y * WW + x) * 64 + cq];
            float4 ww = w4[(ky * 3 + kx) * 64 + cq];
            a.x += v.x * ww.x; a.y += v.y * ww.y; a.z += v.z * ww.z; a.w += v.w * ww.w;
        }
    }
    bf16x4 ob = {(__bf16)a.x, (__bf16)a.y, (__bf16)a.z, (__bf16)a.w};
    ((bf16x4*)out)[(size_t)t * 64 + cq] = ob;
}

// ---------------- GEMM: out[M,N] = A[M,K] @ W[N,K]^T + bias  (m97 structure) ----------------
// EPI 0: f32 out = gemm+bias
// EPI 1: f32 out = gemm+bias+resid
// EPI 2: bf16 out = gelu(gemm+bias)
template <int EPI>
__global__ __launch_bounds__(256, 2)
void gemm_kernel(const __bf16* __restrict__ A, const __bf16* __restrict__ W,
                 const float* __restrict__ bias, const float* __restrict__ resid,
                 float* __restrict__ outf, __bf16* __restrict__ outb,
                 const int Ndim, const int Kdim) {
    __shared__ __align__(16) __bf16 Alds[128 * 32];
    __shared__ __align__(16) __bf16 Blds[128 * 32];

    const int tid  = threadIdx.x;
    const int w    = tid >> 6;
    const int lane = tid & 63;
    const int m0   = blockIdx.x * 128;
    const int n0   = blockIdx.y * 128;
    const int wr   = (w >> 1) * 64;
    const int wc   = (w & 1) * 64;

    f32x4 acc[4][4];
#pragma unroll
    for (int i = 0; i < 4; ++i)
#pragma unroll
        for (int j = 0; j < 4; ++j) acc[i][j] = (f32x4){0.f, 0.f, 0.f, 0.f};

    // staging chunks: 512 x 16B per 128x32 bf16 tile; thread covers chunks c0 and c1
    const int c0 = (w * 2 + 0) * 64 + lane;
    const int c1 = (w * 2 + 1) * 64 + lane;
    const int ar0 = c0 >> 2, ab0 = (c0 & 3) * 16;   // row, k-byte within row (64B rows)
    const int ar1 = c1 >> 2, ab1 = (c1 & 3) * 16;
    int br0 = n0 + ar0; if (br0 > Ndim - 1) br0 = Ndim - 1;   // clamp OOB weight rows
    int br1 = n0 + ar1; if (br1 > Ndim - 1) br1 = Ndim - 1;

    const char* Ab = (const char*)A;
    const char* Wb = (const char*)W;
    char* AL = (char*)Alds;
    char* BL = (char*)Blds;
    const size_t rb = (size_t)Kdim * 2;

    const int mrow = lane & 15;
    const int kofs = (lane >> 4) * 8;

    for (int k0 = 0; k0 < Kdim; k0 += 32) {
        const size_t kb = (size_t)k0 * 2;
        // LDS dest is wave-uniform base; HW adds lane*16
        gl_lds16(Ab + (size_t)(m0 + ar0) * rb + kb + ab0, AL + (w * 2 + 0) * 1024);
        gl_lds16(Ab + (size_t)(m0 + ar1) * rb + kb + ab1, AL + (w * 2 + 1) * 1024);
        gl_lds16(Wb + (size_t)br0 * rb + kb + ab0,        BL + (w * 2 + 0) * 1024);
        gl_lds16(Wb + (size_t)br1 * rb + kb + ab1,        BL + (w * 2 + 1) * 1024);
        __syncthreads();   // compiler drains vmcnt(0) before barrier
        bf16x8 af[4], bfr[4];
#pragma unroll
        for (int i = 0; i < 4; ++i)
            af[i] = *(const bf16x8*)&Alds[(wr + i * 16 + mrow) * 32 + kofs];
#pragma unroll
        for (int i = 0; i < 4; ++i)
            bfr[i] = *(const bf16x8*)&Blds[(wc + i * 16 + mrow) * 32 + kofs];
#pragma unroll
        for (int mi = 0; mi < 4; ++mi)
#pragma unroll
            for (int ni = 0; ni < 4; ++ni)
                acc[mi][ni] = __builtin_amdgcn_mfma_f32_16x16x32_bf16(af[mi], bfr[ni], acc[mi][ni], 0, 0, 0);
        __syncthreads();
    }

    // C/D layout: col = lane&15, row = (lane>>4)*4 + j  (guide §3, m89-verified)
    const int coll = lane & 15;
    const int rowh = (lane >> 4) * 4;
#pragma unroll
    for (int ni = 0; ni < 4; ++ni) {
        const int col = n0 + wc + ni * 16 + coll;
        if (col < Ndim) {
            const float bv = bias[col];
#pragma unroll
            for (int mi = 0; mi < 4; ++mi) {
#pragma unroll
                for (int j = 0; j < 4; ++j) {
                    const int row = m0 + wr + mi * 16 + rowh + j;
                    const size_t idx = (size_t)row * (size_t)Ndim + col;
                    float v = acc[mi][ni][j] + bv;
                    if (EPI == 1) v += resid[idx];
                    if (EPI == 2) { outb[idx] = (__bf16)gelu_exact(v); }
                    else          { outf[idx] = v; }
                }
            }
        }
    }
}

// ---------------- DCNv3 core: block = token, thread = (g, cg) ----------------
__global__ __launch_bounds__(256)
void dcn_kernel(const float* __restrict__ xp, const float* __restrict__ offs,
                const float* __restrict__ masks, __bf16* __restrict__ out) {
    __shared__ float soff[NGRP * NPTS * 2];
    __shared__ float smask[NGRP * NPTS];
    const int t = blockIdx.x;
    const int tid = threadIdx.x;
    for (int i = tid; i < NGRP * NPTS * 2; i += 256) soff[i] = offs[(size_t)t * (NGRP * NPTS * 2) + i];
    if (tid < NGRP * NPTS) smask[tid] = masks[(size_t)t * (NGRP * NPTS) + tid];
    __syncthreads();
    const int g = tid >> 4;
    const int n = t / (HH * WW), hw = t % (HH * WW);
    const int h = hw / WW, w0 = hw % WW;
    // softmax over P=9 (redundant across the 16 channel-lanes of a group)
    float e[NPTS];
    float mx = -1e30f;
#pragma unroll
    for (int p = 0; p < NPTS; ++p) { e[p] = smask[g * NPTS + p]; mx = fmaxf(mx, e[p]); }
    float se = 0.f;
#pragma unroll
    for (int p = 0; p < NPTS; ++p) { e[p] = __expf(e[p] - mx); se += e[p]; }
    const float inv = 1.f / se;
    const float* xn = xp + (size_t)n * (HH * WW) * CCH + tid;  // tid == g*16+cg == channel
    float acc = 0.f;
#pragma unroll
    for (int p = 0; p < NPTS; ++p) {
        const int kx = p / 3, ky = p % 3;  // w-major point order
        // unpadded coords; zeros outside [0,56)^2 == padded grid_sample semantics
        float fx = (float)(w0 + kx - 1) + soff[g * 18 + p * 2 + 0];
        float fy = (float)(h + ky - 1)  + soff[g * 18 + p * 2 + 1];
        float x0f = floorf(fx), y0f = floorf(fy);
        float wx = fx - x0f, wy = fy - y0f;
        int x0 = (int)x0f, y0 = (int)y0f;
        float v00 = 0.f, v10 = 0.f, v01 = 0.f, v11 = 0.f;
        const bool xv0 = (x0 >= 0) && (x0 < WW), xv1 = (x0 + 1 >= 0) && (x0 + 1 < WW);
        const bool yv0 = (y0 >= 0) && (y0 < HH), yv1 = (y0 + 1 >= 0) && (y0 + 1 < HH);
        if (yv0) {
            if (xv0) v00 = xn[(size_t)(y0 * WW + x0) * CCH];
            if (xv1) v10 = xn[(size_t)(y0 * WW + x0 + 1) * CCH];
        }
        if (yv1) {
            if (xv0) v01 = xn[(size_t)((y0 + 1) * WW + x0) * CCH];
            if (xv1) v11 = xn[(size_t)((y0 + 1) * WW + x0 + 1) * CCH];
        }
        float bil = v00 * (1.f - wx) * (1.f - wy) + v10 * wx * (1.f - wy)
                  + v01 * (1.f - wx) * wy         + v11 * wx * wy;
        acc += e[p] * inv * bil;
    }
    out[(size_t)t * CCH + tid] = (__bf16)acc;
}

// ---------------- launch ----------------
extern "C" void kernel_launch(void* const* d_in, const int* in_sizes, int n_in,
                              void* d_out, int out_size, void* d_ws, size_t ws_size,
                              hipStream_t stream) {
    const float* x      = (const float*)d_in[0];
    const float* ln1_g  = (const float*)d_in[1];
    const float* ln1_b  = (const float*)d_in[2];
    const float* dw_w   = (const float*)d_in[3];
    const float* dw_b   = (const float*)d_in[4];
    const float* off_w  = (const float*)d_in[5];
    const float* off_b  = (const float*)d_in[6];
    const float* mask_w = (const float*)d_in[7];
    const float* mask_b = (const float*)d_in[8];
    const float* inp_w  = (const float*)d_in[9];
    const float* inp_b  = (const float*)d_in[10];
    const float* out_w  = (const float*)d_in[11];
    const float* out_b  = (const float*)d_in[12];
    const float* ln2_g  = (const float*)d_in[13];
    const float* ln2_b  = (const float*)d_in[14];
    const float* fc1_w  = (const float*)d_in[15];
    const float* fc1_b  = (const float*)d_in[16];
    const float* fc2_w  = (const float*)d_in[17];
    const float* fc2_b  = (const float*)d_in[18];
    float* out = (float*)d_out;

    char* ws = (char*)d_ws;
    size_t o = 0;
    auto alloc = [&](size_t bytes) { size_t r = o; o += (bytes + 255) & ~(size_t)255; return r; };
    float*  ln1f  = (float*)(ws + alloc((size_t)NTOK * CCH * 4));   // reused as y
    __bf16* lnb   = (__bf16*)(ws + alloc((size_t)NTOK * CCH * 2));  // reused as dcn_bf16
    __bf16* x1b   = (__bf16*)(ws + alloc((size_t)NTOK * CCH * 2));  // reused as ln2_bf16
    float*  xpf   = (float*)(ws + alloc((size_t)NTOK * CCH * 4));   // reused (with offf) as h1
    float*  offf  = (float*)(ws + alloc((size_t)NTOK * 288 * 4));
    float*  maskf = (float*)(ws + alloc((size_t)NTOK * 144 * 4));
    __bf16* wib   = (__bf16*)(ws + alloc((size_t)65536 * 2));
    __bf16* wob   = (__bf16*)(ws + alloc((size_t)65536 * 2));
    __bf16* wfb   = (__bf16*)(ws + alloc((size_t)73728 * 2));
    __bf16* wmb   = (__bf16*)(ws + alloc((size_t)36864 * 2));
    __bf16* w1b   = (__bf16*)(ws + alloc((size_t)262144 * 2));
    __bf16* w2b   = (__bf16*)(ws + alloc((size_t)262144 * 2));
    if (ws_size < o) return;  // workspace too small -> fail loudly (poisoned output)

    float*  yf   = ln1f;
    __bf16* dcnb = lnb;
    __bf16* l2b  = x1b;
    __bf16* h1b  = (__bf16*)xpf;

    // weights -> bf16
    cvt_kernel<<<64, 256, 0, stream>>>(inp_w, wib, 16384);
    cvt_kernel<<<64, 256, 0, stream>>>(out_w, wob, 16384);
    cvt_kernel<<<72, 256, 0, stream>>>(off_w, wfb, 18432);
    cvt_kernel<<<36, 256, 0, stream>>>(mask_w, wmb, 9216);
    cvt_kernel<<<256, 256, 0, stream>>>(fc1_w, w1b, 65536);
    cvt_kernel<<<256, 256, 0, stream>>>(fc2_w, w2b, 65536);

    // LN1 -> f32 (for conv) + bf16 (GEMM A)
    ln_kernel<<<NTOK / 4, 256, 0, stream>>>(x, ln1_g, ln1_b, ln1f, lnb, NTOK);
    // depthwise conv -> x1 bf16
    dwconv_kernel<<<NTOK / 4, 256, 0, stream>>>(ln1f, dw_w, dw_b, x1b);
    // offset / mask / input projections
    gemm_kernel<0><<<dim3(196, 3), 256, 0, stream>>>(x1b, wfb, off_b, nullptr, offf, nullptr, 288, 256);
    gemm_kernel<0><<<dim3(196, 2), 256, 0, stream>>>(x1b, wmb, mask_b, nullptr, maskf, nullptr, 144, 256);
    gemm_kernel<0><<<dim3(196, 2), 256, 0, stream>>>(lnb, wib, inp_b, nullptr, xpf, nullptr, 256, 256);
    // deformable sampling
    dcn_kernel<<<NTOK, 256, 0, stream>>>(xpf, offf, maskf, dcnb);
    // output projection + residual(x) -> y
    gemm_kernel<1><<<dim3(196, 2), 256, 0, stream>>>(dcnb, wob, out_b, x, yf, nullptr, 256, 256);
    // LN2 -> bf16
    ln_kernel<<<NTOK / 4, 256, 0, stream>>>(yf, ln2_g, ln2_b, nullptr, l2b, NTOK);
    // fc1 + exact GELU -> bf16
    gemm_kernel<2><<<dim3(196, 8), 256, 0, stream>>>(l2b, w1b, fc1_b, nullptr, nullptr, h1b, 1024, 256);
    // fc2 + residual(y) -> out
    gemm_kernel<1><<<dim3(196, 2), 256, 0, stream>>>(h1b, w2b, fc2_b, yf, out, nullptr, 256, 1024);
}

// Round 4
// 228.005 us; speedup vs baseline: 1.1896x; 1.1896x over previous
//
#include <hip/hip_runtime.h>
#include <hip/hip_bf16.h>
#include <math.h>

// Problem constants
#define NTOK 25088      // 8*56*56
#define HW_  3136
#define HH   56
#define WW   56
#define CCH  256
#define NGRP 16
#define NPTS 9
#define HIDN 1024
#define NOFFM 432       // merged off(288)+mask(144) row width
#define TPB  4          // tokens per dcn block

typedef __attribute__((ext_vector_type(8))) __bf16 bf16x8;
typedef __attribute__((ext_vector_type(4))) __bf16 bf16x4;
typedef __attribute__((ext_vector_type(4))) float  f32x4;

static __device__ __forceinline__ void gl_lds16(const void* g, void* l) {
    __builtin_amdgcn_global_load_lds((const __attribute__((address_space(1))) void*)g,
                                     (__attribute__((address_space(3))) void*)l, 16, 0, 0);
}

static __device__ __forceinline__ float gelu_exact(float v) {
    return 0.5f * v * (1.0f + erff(v * 0.70710678118654752f));
}

// ---------------- all weight f32->bf16 converts in one kernel ----------------
// segment boundaries in float4 units:
// inp 16384 | out 16384 | off 18432 (->wcat+0) | mask 9216 (->wcat+73728el) | fc1 65536 | fc2 65536
__global__ __launch_bounds__(256)
void cvt_all_kernel(const float* __restrict__ inp_w, const float* __restrict__ out_w,
                    const float* __restrict__ off_w, const float* __restrict__ mask_w,
                    const float* __restrict__ fc1_w, const float* __restrict__ fc2_w,
                    __bf16* wib, __bf16* wob, __bf16* wcat, __bf16* w1b, __bf16* w2b) {
    int i = blockIdx.x * 256 + threadIdx.x;
    const float* s; __bf16* d; int off;
    if (i < 16384)       { s = inp_w;  d = wib;          off = i; }
    else if (i < 32768)  { s = out_w;  d = wob;          off = i - 16384; }
    else if (i < 51200)  { s = off_w;  d = wcat;         off = i - 32768; }
    else if (i < 60416)  { s = mask_w; d = wcat + 73728; off = i - 51200; }
    else if (i < 125952) { s = fc1_w;  d = w1b;          off = i - 60416; }
    else if (i < 191488) { s = fc2_w;  d = w2b;          off = i - 125952; }
    else return;
    float4 v = ((const float4*)s)[off];
    bf16x4 o = {(__bf16)v.x, (__bf16)v.y, (__bf16)v.z, (__bf16)v.w};
    ((bf16x4*)d)[off] = o;
}

__global__ void biascat_kernel(const float* __restrict__ ob, const float* __restrict__ mb,
                               float* __restrict__ bc) {
    int i = threadIdx.x;
    if (i < 288) bc[i] = ob[i];
    else if (i < 432) bc[i] = mb[i - 288];
}

// ---------------- LayerNorm: one wave per token (C=256), bf16 out ----------------
__global__ __launch_bounds__(256)
void ln_kernel(const float* __restrict__ x, const float* __restrict__ g,
               const float* __restrict__ b, __bf16* __restrict__ outb, int ntok) {
    int gid  = blockIdx.x * 256 + threadIdx.x;
    int t    = gid >> 6;
    int lane = threadIdx.x & 63;
    if (t >= ntok) return;
    float4 v = ((const float4*)(x + (size_t)t * CCH))[lane];
    float s = v.x + v.y + v.z + v.w;
#pragma unroll
    for (int o = 1; o < 64; o <<= 1) s += __shfl_xor(s, o);
    float mu = s * 0.00390625f;
    float dx = v.x - mu, dy = v.y - mu, dz = v.z - mu, dw = v.w - mu;
    float q = dx * dx + dy * dy + dz * dz + dw * dw;
#pragma unroll
    for (int o = 1; o < 64; o <<= 1) q += __shfl_xor(q, o);
    float rstd = rsqrtf(q * 0.00390625f + 1e-6f);
    float4 gg = ((const float4*)g)[lane];
    float4 bb = ((const float4*)b)[lane];
    bf16x4 ob = {(__bf16)(dx * rstd * gg.x + bb.x), (__bf16)(dy * rstd * gg.y + bb.y),
                 (__bf16)(dz * rstd * gg.z + bb.z), (__bf16)(dw * rstd * gg.w + bb.w)};
    ((bf16x4*)(outb + (size_t)t * CCH))[lane] = ob;
}

// ---------------- depthwise 3x3 conv (pad 1), bf16 in, thread = token x 4 channels ----------------
__global__ __launch_bounds__(256)
void dwconv_kernel(const __bf16* __restrict__ ln, const float* __restrict__ wt,
                   const float* __restrict__ bias, __bf16* __restrict__ out) {
    int gid = blockIdx.x * 256 + threadIdx.x;
    int t = gid >> 6;
    int cq = gid & 63;
    if (t >= NTOK) return;
    int n = t / HW_, hw = t % HW_;
    int h = hw / WW, w0 = hw % WW;
    float4 a = ((const float4*)bias)[cq];
    const bf16x4* l4 = (const bf16x4*)ln;
    const float4* w4 = (const float4*)wt;
#pragma unroll
    for (int ky = 0; ky < 3; ++ky) {
        int y = h + ky - 1;
        if (y < 0 || y >= HH) continue;
#pragma unroll
        for (int kx = 0; kx < 3; ++kx) {
            int x = w0 + kx - 1;
            if (x < 0 || x >= WW) continue;
            bf16x4 v = l4[(size_t)(n * HW_ + y * WW + x) * 64 + cq];
            float4 ww = w4[(ky * 3 + kx) * 64 + cq];
            a.x += (float)v[0] * ww.x; a.y += (float)v[1] * ww.y;
            a.z += (float)v[2] * ww.z; a.w += (float)v[3] * ww.w;
        }
    }
    bf16x4 ob = {(__bf16)a.x, (__bf16)a.y, (__bf16)a.z, (__bf16)a.w};
    ((bf16x4*)out)[(size_t)t * 64 + cq] = ob;
}

// ---------------- GEMM: out[M,N] = A[M,K] @ W[N,K]^T + bias  (m97 structure) ----------------
// EPI 0: f32 out = gemm+bias ; EPI 1: f32 out = gemm+bias+resid ; EPI 2: bf16 out = gelu(gemm+bias)
template <int EPI>
__global__ __launch_bounds__(256, 2)
void gemm_kernel(const __bf16* __restrict__ A, const __bf16* __restrict__ W,
                 const float* __restrict__ bias, const float* __restrict__ resid,
                 float* __restrict__ outf, __bf16* __restrict__ outb,
                 const int Ndim, const int Kdim) {
    __shared__ __align__(16) __bf16 Alds[128 * 32];
    __shared__ __align__(16) __bf16 Blds[128 * 32];

    const int tid  = threadIdx.x;
    const int w    = tid >> 6;
    const int lane = tid & 63;
    const int m0   = blockIdx.x * 128;
    const int n0   = blockIdx.y * 128;
    const int wr   = (w >> 1) * 64;
    const int wc   = (w & 1) * 64;

    f32x4 acc[4][4];
#pragma unroll
    for (int i = 0; i < 4; ++i)
#pragma unroll
        for (int j = 0; j < 4; ++j) acc[i][j] = (f32x4){0.f, 0.f, 0.f, 0.f};

    const int c0 = (w * 2 + 0) * 64 + lane;
    const int c1 = (w * 2 + 1) * 64 + lane;
    const int ar0 = c0 >> 2, ab0 = (c0 & 3) * 16;
    const int ar1 = c1 >> 2, ab1 = (c1 & 3) * 16;
    int br0 = n0 + ar0; if (br0 > Ndim - 1) br0 = Ndim - 1;
    int br1 = n0 + ar1; if (br1 > Ndim - 1) br1 = Ndim - 1;

    const char* Ab = (const char*)A;
    const char* Wb = (const char*)W;
    char* AL = (char*)Alds;
    char* BL = (char*)Blds;
    const size_t rb = (size_t)Kdim * 2;

    const int mrow = lane & 15;
    const int kofs = (lane >> 4) * 8;

    for (int k0 = 0; k0 < Kdim; k0 += 32) {
        const size_t kb = (size_t)k0 * 2;
        gl_lds16(Ab + (size_t)(m0 + ar0) * rb + kb + ab0, AL + (w * 2 + 0) * 1024);
        gl_lds16(Ab + (size_t)(m0 + ar1) * rb + kb + ab1, AL + (w * 2 + 1) * 1024);
        gl_lds16(Wb + (size_t)br0 * rb + kb + ab0,        BL + (w * 2 + 0) * 1024);
        gl_lds16(Wb + (size_t)br1 * rb + kb + ab1,        BL + (w * 2 + 1) * 1024);
        __syncthreads();
        bf16x8 af[4], bfr[4];
#pragma unroll
        for (int i = 0; i < 4; ++i)
            af[i] = *(const bf16x8*)&Alds[(wr + i * 16 + mrow) * 32 + kofs];
#pragma unroll
        for (int i = 0; i < 4; ++i)
            bfr[i] = *(const bf16x8*)&Blds[(wc + i * 16 + mrow) * 32 + kofs];
#pragma unroll
        for (int mi = 0; mi < 4; ++mi)
#pragma unroll
            for (int ni = 0; ni < 4; ++ni)
                acc[mi][ni] = __builtin_amdgcn_mfma_f32_16x16x32_bf16(af[mi], bfr[ni], acc[mi][ni], 0, 0, 0);
        __syncthreads();
    }

    const int coll = lane & 15;
    const int rowh = (lane >> 4) * 4;
#pragma unroll
    for (int ni = 0; ni < 4; ++ni) {
        const int col = n0 + wc + ni * 16 + coll;
        if (col < Ndim) {
            const float bv = bias[col];
#pragma unroll
            for (int mi = 0; mi < 4; ++mi) {
#pragma unroll
                for (int j = 0; j < 4; ++j) {
                    const int row = m0 + wr + mi * 16 + rowh + j;
                    const size_t idx = (size_t)row * (size_t)Ndim + col;
                    float v = acc[mi][ni][j] + bv;
                    if (EPI == 1) v += resid[idx];
                    if (EPI == 2) { outb[idx] = (__bf16)gelu_exact(v); }
                    else          { outf[idx] = v; }
                }
            }
        }
    }
}

// ---------------- DCNv3 core: block = 4 tokens; tap precompute in LDS ----------------
__global__ __launch_bounds__(256)
void dcn_kernel(const float* __restrict__ xp, const float* __restrict__ om,
                __bf16* __restrict__ out) {
    __shared__ float  raw[TPB][NOFFM];            // offsets[0,288) + mask[288,432)
    __shared__ int4   sidx[NPTS][TPB * NGRP];     // 4 clamped tap indices (y*W+x)
    __shared__ float4 swt[NPTS][TPB * NGRP];      // 4 bilinear weights * softmax(mask)
    const int tid = threadIdx.x;
    const int t0  = blockIdx.x * TPB;

    // A: stage merged off/mask rows (coalesced)
    for (int i = tid; i < TPB * NOFFM; i += 256)
        raw[i / NOFFM][i % NOFFM] = om[(size_t)t0 * NOFFM + i];
    __syncthreads();

    // B: per-(token,group) softmax over 9 points, premultiplied in place
    if (tid < TPB * NGRP) {
        const int lt = tid >> 4, g = tid & 15;
        float* m = &raw[lt][288 + g * 9];
        float mx = m[0];
#pragma unroll
        for (int p = 1; p < 9; ++p) mx = fmaxf(mx, m[p]);
        float s = 0.f, e[9];
#pragma unroll
        for (int p = 0; p < 9; ++p) { e[p] = __expf(m[p] - mx); s += e[p]; }
        const float inv = 1.f / s;
#pragma unroll
        for (int p = 0; p < 9; ++p) m[p] = e[p] * inv;
    }
    __syncthreads();

    // C: tap precompute, one entry per (lt, g, p)
    for (int e = tid; e < TPB * NGRP * NPTS; e += 256) {
        const int lt = e / 144, r = e % 144, g = r / 9, p = r % 9;
        const int t  = t0 + lt;
        const int hw = t % HW_;
        const int h = hw / WW, w0 = hw % WW;
        const float offx = raw[lt][g * 18 + p * 2 + 0];
        const float offy = raw[lt][g * 18 + p * 2 + 1];
        const float pm   = raw[lt][288 + g * 9 + p];
        const int kx = p / 3, ky = p % 3;          // w-major point order
        const float fx = (float)(w0 + kx - 1) + offx;
        const float fy = (float)(h  + ky - 1) + offy;
        const float x0f = floorf(fx), y0f = floorf(fy);
        const float wx = fx - x0f, wy = fy - y0f;
        const int x0 = (int)x0f, y0 = (int)y0f;
        const bool xv0 = (unsigned)x0 < WW, xv1 = (unsigned)(x0 + 1) < WW;
        const bool yv0 = (unsigned)y0 < HH, yv1 = (unsigned)(y0 + 1) < HH;
        const int xc0 = min(max(x0, 0), WW - 1), xc1 = min(max(x0 + 1, 0), WW - 1);
        const int yc0 = min(max(y0, 0), HH - 1), yc1 = min(max(y0 + 1, 0), HH - 1);
        const int tg = lt * 16 + g;
        sidx[p][tg] = make_int4(yc0 * WW + xc0, yc0 * WW + xc1, yc1 * WW + xc0, yc1 * WW + xc1);
        swt[p][tg]  = make_float4((xv0 && yv0) ? (1.f - wx) * (1.f - wy) * pm : 0.f,
                                  (xv1 && yv0) ? wx * (1.f - wy) * pm : 0.f,
                                  (xv0 && yv1) ? (1.f - wx) * wy * pm : 0.f,
                                  (xv1 && yv1) ? wx * wy * pm : 0.f);
    }
    __syncthreads();

    // D: gather. thread = (lt, g, cq); channel base = lane*4 (== g*16 + cq*4)
    const int lt = tid >> 6, lane = tid & 63;
    const int g = lane >> 2;
    const int t = t0 + lt;
    const int n = t / HW_;
    const int tg = lt * 16 + g;
    const float* base = xp + (size_t)n * HW_ * CCH + lane * 4;
    f32x4 acc = {0.f, 0.f, 0.f, 0.f};
#pragma unroll
    for (int p = 0; p < NPTS; ++p) {
        const int4   id = sidx[p][tg];
        const float4 wv = swt[p][tg];
        f32x4 v0 = *(const f32x4*)(base + (size_t)id.x * CCH);
        f32x4 v1 = *(const f32x4*)(base + (size_t)id.y * CCH);
        f32x4 v2 = *(const f32x4*)(base + (size_t)id.z * CCH);
        f32x4 v3 = *(const f32x4*)(base + (size_t)id.w * CCH);
        acc += wv.x * v0 + wv.y * v1 + wv.z * v2 + wv.w * v3;
    }
    bf16x4 ob = {(__bf16)acc.x, (__bf16)acc.y, (__bf16)acc.z, (__bf16)acc.w};
    ((bf16x4*)out)[(size_t)t * 64 + lane] = ob;
}

// ---------------- launch ----------------
extern "C" void kernel_launch(void* const* d_in, const int* in_sizes, int n_in,
                              void* d_out, int out_size, void* d_ws, size_t ws_size,
                              hipStream_t stream) {
    const float* x      = (const float*)d_in[0];
    const float* ln1_g  = (const float*)d_in[1];
    const float* ln1_b  = (const float*)d_in[2];
    const float* dw_w   = (const float*)d_in[3];
    const float* dw_b   = (const float*)d_in[4];
    const float* off_w  = (const float*)d_in[5];
    const float* off_b  = (const float*)d_in[6];
    const float* mask_w = (const float*)d_in[7];
    const float* mask_b = (const float*)d_in[8];
    const float* inp_w  = (const float*)d_in[9];
    const float* inp_b  = (const float*)d_in[10];
    const float* out_w  = (const float*)d_in[11];
    const float* out_b  = (const float*)d_in[12];
    const float* ln2_g  = (const float*)d_in[13];
    const float* ln2_b  = (const float*)d_in[14];
    const float* fc1_w  = (const float*)d_in[15];
    const float* fc1_b  = (const float*)d_in[16];
    const float* fc2_w  = (const float*)d_in[17];
    const float* fc2_b  = (const float*)d_in[18];
    float* out = (float*)d_out;

    char* ws = (char*)d_ws;
    size_t o = 0;
    auto alloc = [&](size_t bytes) { size_t r = o; o += (bytes + 255) & ~(size_t)255; return r; };
    float*  yf    = (float*)(ws + alloc((size_t)NTOK * CCH * 4));    // y buffer
    __bf16* lnb   = (__bf16*)(ws + alloc((size_t)NTOK * CCH * 2));   // reused as dcnb
    __bf16* x1b   = (__bf16*)(ws + alloc((size_t)NTOK * CCH * 2));   // reused as l2b
    float*  xpf   = (float*)(ws + alloc((size_t)NTOK * CCH * 4));    // reused (+offm) as h1b
    float*  offm  = (float*)(ws + alloc((size_t)NTOK * NOFFM * 4));  // merged off+mask
    __bf16* wib   = (__bf16*)(ws + alloc((size_t)65536 * 2));
    __bf16* wob   = (__bf16*)(ws + alloc((size_t)65536 * 2));
    __bf16* wcat  = (__bf16*)(ws + alloc((size_t)110592 * 2));       // off(288)+mask(144) x 256
    __bf16* w1b   = (__bf16*)(ws + alloc((size_t)262144 * 2));
    __bf16* w2b   = (__bf16*)(ws + alloc((size_t)262144 * 2));
    float*  bcat  = (float*)(ws + alloc((size_t)432 * 4));
    if (ws_size < o) return;

    __bf16* dcnb = lnb;
    __bf16* l2b  = x1b;
    __bf16* h1b  = (__bf16*)xpf;   // 51.4MB: spills into offm region (free by then)

    // weights -> bf16 (one kernel) + bias concat
    cvt_all_kernel<<<748, 256, 0, stream>>>(inp_w, out_w, off_w, mask_w, fc1_w, fc2_w,
                                            wib, wob, wcat, w1b, w2b);
    biascat_kernel<<<1, 512, 0, stream>>>(off_b, mask_b, bcat);

    // LN1 -> bf16
    ln_kernel<<<NTOK / 4, 256, 0, stream>>>(x, ln1_g, ln1_b, lnb, NTOK);
    // depthwise conv (bf16 in) -> x1 bf16
    dwconv_kernel<<<NTOK / 4, 256, 0, stream>>>(lnb, dw_w, dw_b, x1b);
    // merged offset+mask projection (N=432)
    gemm_kernel<0><<<dim3(196, 4), 256, 0, stream>>>(x1b, wcat, bcat, nullptr, offm, nullptr, NOFFM, 256);
    // input projection
    gemm_kernel<0><<<dim3(196, 2), 256, 0, stream>>>(lnb, wib, inp_b, nullptr, xpf, nullptr, 256, 256);
    // deformable sampling
    dcn_kernel<<<NTOK / TPB, 256, 0, stream>>>(xpf, offm, dcnb);
    // output projection + residual(x) -> y
    gemm_kernel<1><<<dim3(196, 2), 256, 0, stream>>>(dcnb, wob, out_b, x, yf, nullptr, 256, 256);
    // LN2 -> bf16
    ln_kernel<<<NTOK / 4, 256, 0, stream>>>(yf, ln2_g, ln2_b, l2b, NTOK);
    // fc1 + exact GELU -> bf16
    gemm_kernel<2><<<dim3(196, 8), 256, 0, stream>>>(l2b, w1b, fc1_b, nullptr, nullptr, h1b, 1024, 256);
    // fc2 + residual(y) -> out
    gemm_kernel<1><<<dim3(196, 2), 256, 0, stream>>>(h1b, w2b, fc2_b, yf, out, nullptr, 256, 1024);
}

// Round 5
// 214.908 us; speedup vs baseline: 1.2621x; 1.0609x over previous
//
#include <hip/hip_runtime.h>
#include <hip/hip_bf16.h>
#include <math.h>

// Problem constants
#define NTOK 25088      // 8*56*56
#define HW_  3136
#define HH   56
#define WW   56
#define CCH  256
#define NGRP 16
#define NPTS 9
#define HIDN 1024
#define NOFFM 432       // merged off(288)+mask(144) row width
#define TPB  4          // tokens per dcn block

typedef __attribute__((ext_vector_type(8))) __bf16 bf16x8;
typedef __attribute__((ext_vector_type(4))) __bf16 bf16x4;
typedef __attribute__((ext_vector_type(4))) float  f32x4;

static __device__ __forceinline__ void gl_lds16(const void* g, void* l) {
    __builtin_amdgcn_global_load_lds((const __attribute__((address_space(1))) void*)g,
                                     (__attribute__((address_space(3))) void*)l, 16, 0, 0);
}

// tanh-form GELU: max |err| vs exact erf-gelu ~3e-4 (amplified ~5e-4 through fc2)
static __device__ __forceinline__ float gelu_fast(float v) {
    float z = 0.7978845608028654f * (v + 0.044715f * v * v * v);
    // tanh(z) = 1 - 2/(exp(2z)+1)
    float t = 1.0f - 2.0f / (__expf(2.0f * z) + 1.0f);
    return 0.5f * v * (1.0f + t);
}

// ---------------- all weight f32->bf16 converts in one kernel ----------------
__global__ __launch_bounds__(256)
void cvt_all_kernel(const float* __restrict__ inp_w, const float* __restrict__ out_w,
                    const float* __restrict__ off_w, const float* __restrict__ mask_w,
                    const float* __restrict__ fc1_w, const float* __restrict__ fc2_w,
                    __bf16* wib, __bf16* wob, __bf16* wcat, __bf16* w1b, __bf16* w2b) {
    int i = blockIdx.x * 256 + threadIdx.x;
    const float* s; __bf16* d; int off;
    if (i < 16384)       { s = inp_w;  d = wib;          off = i; }
    else if (i < 32768)  { s = out_w;  d = wob;          off = i - 16384; }
    else if (i < 51200)  { s = off_w;  d = wcat;         off = i - 32768; }
    else if (i < 60416)  { s = mask_w; d = wcat + 73728; off = i - 51200; }
    else if (i < 125952) { s = fc1_w;  d = w1b;          off = i - 60416; }
    else if (i < 191488) { s = fc2_w;  d = w2b;          off = i - 125952; }
    else return;
    float4 v = ((const float4*)s)[off];
    bf16x4 o = {(__bf16)v.x, (__bf16)v.y, (__bf16)v.z, (__bf16)v.w};
    ((bf16x4*)d)[off] = o;
}

__global__ void biascat_kernel(const float* __restrict__ ob, const float* __restrict__ mb,
                               float* __restrict__ bc) {
    int i = threadIdx.x;
    if (i < 288) bc[i] = ob[i];
    else if (i < 432) bc[i] = mb[i - 288];
}

// ---------------- LayerNorm: one wave per token (C=256), bf16 out ----------------
__global__ __launch_bounds__(256)
void ln_kernel(const float* __restrict__ x, const float* __restrict__ g,
               const float* __restrict__ b, __bf16* __restrict__ outb, int ntok) {
    int gid  = blockIdx.x * 256 + threadIdx.x;
    int t    = gid >> 6;
    int lane = threadIdx.x & 63;
    if (t >= ntok) return;
    float4 v = ((const float4*)(x + (size_t)t * CCH))[lane];
    float s = v.x + v.y + v.z + v.w;
#pragma unroll
    for (int o = 1; o < 64; o <<= 1) s += __shfl_xor(s, o);
    float mu = s * 0.00390625f;
    float dx = v.x - mu, dy = v.y - mu, dz = v.z - mu, dw = v.w - mu;
    float q = dx * dx + dy * dy + dz * dz + dw * dw;
#pragma unroll
    for (int o = 1; o < 64; o <<= 1) q += __shfl_xor(q, o);
    float rstd = rsqrtf(q * 0.00390625f + 1e-6f);
    float4 gg = ((const float4*)g)[lane];
    float4 bb = ((const float4*)b)[lane];
    bf16x4 ob = {(__bf16)(dx * rstd * gg.x + bb.x), (__bf16)(dy * rstd * gg.y + bb.y),
                 (__bf16)(dz * rstd * gg.z + bb.z), (__bf16)(dw * rstd * gg.w + bb.w)};
    ((bf16x4*)(outb + (size_t)t * CCH))[lane] = ob;
}

// ---------------- depthwise 3x3 conv (pad 1), bf16 in, thread = token x 4 channels ----------------
__global__ __launch_bounds__(256)
void dwconv_kernel(const __bf16* __restrict__ ln, const float* __restrict__ wt,
                   const float* __restrict__ bias, __bf16* __restrict__ out) {
    int gid = blockIdx.x * 256 + threadIdx.x;
    int t = gid >> 6;
    int cq = gid & 63;
    if (t >= NTOK) return;
    int n = t / HW_, hw = t % HW_;
    int h = hw / WW, w0 = hw % WW;
    float4 a = ((const float4*)bias)[cq];
    const bf16x4* l4 = (const bf16x4*)ln;
    const float4* w4 = (const float4*)wt;
#pragma unroll
    for (int ky = 0; ky < 3; ++ky) {
        int y = h + ky - 1;
        if (y < 0 || y >= HH) continue;
#pragma unroll
        for (int kx = 0; kx < 3; ++kx) {
            int x = w0 + kx - 1;
            if (x < 0 || x >= WW) continue;
            bf16x4 v = l4[(size_t)(n * HW_ + y * WW + x) * 64 + cq];
            float4 ww = w4[(ky * 3 + kx) * 64 + cq];
            a.x += (float)v[0] * ww.x; a.y += (float)v[1] * ww.y;
            a.z += (float)v[2] * ww.z; a.w += (float)v[3] * ww.w;
        }
    }
    bf16x4 ob = {(__bf16)a.x, (__bf16)a.y, (__bf16)a.z, (__bf16)a.w};
    ((bf16x4*)out)[(size_t)t * 64 + cq] = ob;
}

// ---------------- GEMM: out[M,N] = A[M,K] @ W[N,K]^T + bias ----------------
// m97 structure + 16B-granule XOR swizzle (chunk ^= (row>>2)&3) on LDS staging/reads,
// B-fragment remap (rows wc+4*mrow+ni) so each lane owns 4 consecutive output cols
// -> vectorized float4 / bf16x4 epilogue.
// EPI 0: f32 out = gemm+bias ; EPI 1: f32 out = gemm+bias+resid ; EPI 2: bf16 out = gelu(gemm+bias)
template <int EPI>
__global__ __launch_bounds__(256, 4)
void gemm_kernel(const __bf16* __restrict__ A, const __bf16* __restrict__ W,
                 const float* __restrict__ bias, const float* __restrict__ resid,
                 float* __restrict__ outf, __bf16* __restrict__ outb,
                 const int Ndim, const int Kdim) {
    __shared__ __align__(16) __bf16 Alds[128 * 32];
    __shared__ __align__(16) __bf16 Blds[128 * 32];

    const int tid  = threadIdx.x;
    const int w    = tid >> 6;
    const int lane = tid & 63;
    const int m0   = blockIdx.x * 128;
    const int n0   = blockIdx.y * 128;
    const int wr   = (w >> 1) * 64;
    const int wc   = (w & 1) * 64;

    f32x4 acc[4][4];
#pragma unroll
    for (int i = 0; i < 4; ++i)
#pragma unroll
        for (int j = 0; j < 4; ++j) acc[i][j] = (f32x4){0.f, 0.f, 0.f, 0.f};

    // staging: 512 x 16B chunk-positions per 128x32 tile; position p -> (row=p>>2, slot=p&3)
    // slot holds global chunk (slot ^ s(row)), s(row)=(row>>2)&3  [= (p>>4)&3]
    const int c0 = (w * 2 + 0) * 64 + lane;
    const int c1 = (w * 2 + 1) * 64 + lane;
    const int ar0 = c0 >> 2, ab0 = ((c0 & 3) ^ ((c0 >> 4) & 3)) * 16;
    const int ar1 = c1 >> 2, ab1 = ((c1 & 3) ^ ((c1 >> 4) & 3)) * 16;
    int br0 = n0 + ar0; if (br0 > Ndim - 1) br0 = Ndim - 1;
    int br1 = n0 + ar1; if (br1 > Ndim - 1) br1 = Ndim - 1;

    const char* Ab = (const char*)A;
    const char* Wb = (const char*)W;
    char* AL = (char*)Alds;
    char* BL = (char*)Blds;
    const size_t rb = (size_t)Kdim * 2;

    const int mrow = lane & 15;
    const int q    = lane >> 4;
    const int kA   = ((q ^ (mrow >> 2)) & 3) * 16;   // A-read: s(row) = (mrow>>2)&3
    const int kB   = ((q ^ mrow) & 3) * 16;          // B-read: s(row) = mrow&3

    for (int k0 = 0; k0 < Kdim; k0 += 32) {
        const size_t kb = (size_t)k0 * 2;
        gl_lds16(Ab + (size_t)(m0 + ar0) * rb + kb + ab0, AL + (w * 2 + 0) * 1024);
        gl_lds16(Ab + (size_t)(m0 + ar1) * rb + kb + ab1, AL + (w * 2 + 1) * 1024);
        gl_lds16(Wb + (size_t)br0 * rb + kb + ab0,        BL + (w * 2 + 0) * 1024);
        gl_lds16(Wb + (size_t)br1 * rb + kb + ab1,        BL + (w * 2 + 1) * 1024);
        __syncthreads();
        bf16x8 af[4], bfr[4];
#pragma unroll
        for (int i = 0; i < 4; ++i)
            af[i] = *(const bf16x8*)(AL + (wr + i * 16 + mrow) * 64 + kA);
#pragma unroll
        for (int i = 0; i < 4; ++i)
            bfr[i] = *(const bf16x8*)(BL + (wc + 4 * mrow + i) * 64 + kB);
#pragma unroll
        for (int mi = 0; mi < 4; ++mi)
#pragma unroll
            for (int ni = 0; ni < 4; ++ni)
                acc[mi][ni] = __builtin_amdgcn_mfma_f32_16x16x32_bf16(af[mi], bfr[ni], acc[mi][ni], 0, 0, 0);
        __syncthreads();
    }

    // C/D layout: slot (lane&15) of B-frag ni = W-row wc+4*(lane&15)+ni
    // -> lane owns cols col0..col0+3, rows (lane>>4)*4 + j per mi.
    const int coll = lane & 15;
    const int rowh = (lane >> 4) * 4;
    const int col0 = n0 + wc + 4 * coll;
    if (col0 < Ndim) {
        const float4 bv = *(const float4*)(bias + col0);
#pragma unroll
        for (int mi = 0; mi < 4; ++mi) {
#pragma unroll
            for (int j = 0; j < 4; ++j) {
                const int row = m0 + wr + mi * 16 + rowh + j;
                const size_t idx = (size_t)row * (size_t)Ndim + col0;
                float4 v = make_float4(acc[mi][0][j] + bv.x, acc[mi][1][j] + bv.y,
                                       acc[mi][2][j] + bv.z, acc[mi][3][j] + bv.w);
                if (EPI == 1) {
                    const float4 r = *(const float4*)(resid + idx);
                    v.x += r.x; v.y += r.y; v.z += r.z; v.w += r.w;
                }
                if (EPI == 2) {
                    bf16x4 ob = {(__bf16)gelu_fast(v.x), (__bf16)gelu_fast(v.y),
                                 (__bf16)gelu_fast(v.z), (__bf16)gelu_fast(v.w)};
                    *(bf16x4*)(outb + idx) = ob;
                } else {
                    *(float4*)(outf + idx) = v;
                }
            }
        }
    }
}

// ---------------- DCNv3 core: block = 4 tokens; tap precompute in LDS ----------------
__global__ __launch_bounds__(256)
void dcn_kernel(const float* __restrict__ xp, const float* __restrict__ om,
                __bf16* __restrict__ out) {
    __shared__ float  raw[TPB][NOFFM];            // offsets[0,288) + mask[288,432)
    __shared__ int4   sidx[NPTS][TPB * NGRP];     // 4 clamped tap indices (y*W+x)
    __shared__ float4 swt[NPTS][TPB * NGRP];      // 4 bilinear weights * softmax(mask)
    const int tid = threadIdx.x;
    const int t0  = blockIdx.x * TPB;

    for (int i = tid; i < TPB * NOFFM; i += 256)
        raw[i / NOFFM][i % NOFFM] = om[(size_t)t0 * NOFFM + i];
    __syncthreads();

    if (tid < TPB * NGRP) {
        const int lt = tid >> 4, g = tid & 15;
        float* m = &raw[lt][288 + g * 9];
        float mx = m[0];
#pragma unroll
        for (int p = 1; p < 9; ++p) mx = fmaxf(mx, m[p]);
        float s = 0.f, e[9];
#pragma unroll
        for (int p = 0; p < 9; ++p) { e[p] = __expf(m[p] - mx); s += e[p]; }
        const float inv = 1.f / s;
#pragma unroll
        for (int p = 0; p < 9; ++p) m[p] = e[p] * inv;
    }
    __syncthreads();

    for (int e = tid; e < TPB * NGRP * NPTS; e += 256) {
        const int lt = e / 144, r = e % 144, g = r / 9, p = r % 9;
        const int t  = t0 + lt;
        const int hw = t % HW_;
        const int h = hw / WW, w0 = hw % WW;
        const float offx = raw[lt][g * 18 + p * 2 + 0];
        const float offy = raw[lt][g * 18 + p * 2 + 1];
        const float pm   = raw[lt][288 + g * 9 + p];
        const int kx = p / 3, ky = p % 3;          // w-major point order
        const float fx = (float)(w0 + kx - 1) + offx;
        const float fy = (float)(h  + ky - 1) + offy;
        const float x0f = floorf(fx), y0f = floorf(fy);
        const float wx = fx - x0f, wy = fy - y0f;
        const int x0 = (int)x0f, y0 = (int)y0f;
        const bool xv0 = (unsigned)x0 < WW, xv1 = (unsigned)(x0 + 1) < WW;
        const bool yv0 = (unsigned)y0 < HH, yv1 = (unsigned)(y0 + 1) < HH;
        const int xc0 = min(max(x0, 0), WW - 1), xc1 = min(max(x0 + 1, 0), WW - 1);
        const int yc0 = min(max(y0, 0), HH - 1), yc1 = min(max(y0 + 1, 0), HH - 1);
        const int tg = lt * 16 + g;
        sidx[p][tg] = make_int4(yc0 * WW + xc0, yc0 * WW + xc1, yc1 * WW + xc0, yc1 * WW + xc1);
        swt[p][tg]  = make_float4((xv0 && yv0) ? (1.f - wx) * (1.f - wy) * pm : 0.f,
                                  (xv1 && yv0) ? wx * (1.f - wy) * pm : 0.f,
                                  (xv0 && yv1) ? (1.f - wx) * wy * pm : 0.f,
                                  (xv1 && yv1) ? wx * wy * pm : 0.f);
    }
    __syncthreads();

    const int lt = tid >> 6, lane = tid & 63;
    const int g = lane >> 2;
    const int t = t0 + lt;
    const int n = t / HW_;
    const int tg = lt * 16 + g;
    const float* base = xp + (size_t)n * HW_ * CCH + lane * 4;
    f32x4 acc = {0.f, 0.f, 0.f, 0.f};
#pragma unroll
    for (int p = 0; p < NPTS; ++p) {
        const int4   id = sidx[p][tg];
        const float4 wv = swt[p][tg];
        f32x4 v0 = *(const f32x4*)(base + (size_t)id.x * CCH);
        f32x4 v1 = *(const f32x4*)(base + (size_t)id.y * CCH);
        f32x4 v2 = *(const f32x4*)(base + (size_t)id.z * CCH);
        f32x4 v3 = *(const f32x4*)(base + (size_t)id.w * CCH);
        acc += wv.x * v0 + wv.y * v1 + wv.z * v2 + wv.w * v3;
    }
    bf16x4 ob = {(__bf16)acc.x, (__bf16)acc.y, (__bf16)acc.z, (__bf16)acc.w};
    ((bf16x4*)out)[(size_t)t * 64 + lane] = ob;
}

// ---------------- launch ----------------
extern "C" void kernel_launch(void* const* d_in, const int* in_sizes, int n_in,
                              void* d_out, int out_size, void* d_ws, size_t ws_size,
                              hipStream_t stream) {
    const float* x      = (const float*)d_in[0];
    const float* ln1_g  = (const float*)d_in[1];
    const float* ln1_b  = (const float*)d_in[2];
    const float* dw_w   = (const float*)d_in[3];
    const float* dw_b   = (const float*)d_in[4];
    const float* off_w  = (const float*)d_in[5];
    const float* off_b  = (const float*)d_in[6];
    const float* mask_w = (const float*)d_in[7];
    const float* mask_b = (const float*)d_in[8];
    const float* inp_w  = (const float*)d_in[9];
    const float* inp_b  = (const float*)d_in[10];
    const float* out_w  = (const float*)d_in[11];
    const float* out_b  = (const float*)d_in[12];
    const float* ln2_g  = (const float*)d_in[13];
    const float* ln2_b  = (const float*)d_in[14];
    const float* fc1_w  = (const float*)d_in[15];
    const float* fc1_b  = (const float*)d_in[16];
    const float* fc2_w  = (const float*)d_in[17];
    const float* fc2_b  = (const float*)d_in[18];
    float* out = (float*)d_out;

    char* ws = (char*)d_ws;
    size_t o = 0;
    auto alloc = [&](size_t bytes) { size_t r = o; o += (bytes + 255) & ~(size_t)255; return r; };
    float*  yf    = (float*)(ws + alloc((size_t)NTOK * CCH * 4));    // y buffer
    __bf16* lnb   = (__bf16*)(ws + alloc((size_t)NTOK * CCH * 2));   // reused as dcnb
    __bf16* x1b   = (__bf16*)(ws + alloc((size_t)NTOK * CCH * 2));   // reused as l2b
    float*  xpf   = (float*)(ws + alloc((size_t)NTOK * CCH * 4));    // reused (+offm) as h1b
    float*  offm  = (float*)(ws + alloc((size_t)NTOK * NOFFM * 4));  // merged off+mask
    __bf16* wib   = (__bf16*)(ws + alloc((size_t)65536 * 2));
    __bf16* wob   = (__bf16*)(ws + alloc((size_t)65536 * 2));
    __bf16* wcat  = (__bf16*)(ws + alloc((size_t)110592 * 2));       // off(288)+mask(144) x 256
    __bf16* w1b   = (__bf16*)(ws + alloc((size_t)262144 * 2));
    __bf16* w2b   = (__bf16*)(ws + alloc((size_t)262144 * 2));
    float*  bcat  = (float*)(ws + alloc((size_t)432 * 4));
    if (ws_size < o) return;

    __bf16* dcnb = lnb;
    __bf16* l2b  = x1b;
    __bf16* h1b  = (__bf16*)xpf;   // 51.4MB: spills into offm region (free by then)

    cvt_all_kernel<<<748, 256, 0, stream>>>(inp_w, out_w, off_w, mask_w, fc1_w, fc2_w,
                                            wib, wob, wcat, w1b, w2b);
    biascat_kernel<<<1, 512, 0, stream>>>(off_b, mask_b, bcat);

    ln_kernel<<<NTOK / 4, 256, 0, stream>>>(x, ln1_g, ln1_b, lnb, NTOK);
    dwconv_kernel<<<NTOK / 4, 256, 0, stream>>>(lnb, dw_w, dw_b, x1b);
    gemm_kernel<0><<<dim3(196, 4), 256, 0, stream>>>(x1b, wcat, bcat, nullptr, offm, nullptr, NOFFM, 256);
    gemm_kernel<0><<<dim3(196, 2), 256, 0, stream>>>(lnb, wib, inp_b, nullptr, xpf, nullptr, 256, 256);
    dcn_kernel<<<NTOK / TPB, 256, 0, stream>>>(xpf, offm, dcnb);
    gemm_kernel<1><<<dim3(196, 2), 256, 0, stream>>>(dcnb, wob, out_b, x, yf, nullptr, 256, 256);
    ln_kernel<<<NTOK / 4, 256, 0, stream>>>(yf, ln2_g, ln2_b, l2b, NTOK);
    gemm_kernel<2><<<dim3(196, 8), 256, 0, stream>>>(l2b, w1b, fc1_b, nullptr, nullptr, h1b, 1024, 256);
    gemm_kernel<1><<<dim3(196, 2), 256, 0, stream>>>(h1b, w2b, fc2_b, yf, out, nullptr, 256, 1024);
}

// Round 6
// 196.558 us; speedup vs baseline: 1.3799x; 1.0934x over previous
//
#include <hip/hip_runtime.h>
#include <hip/hip_bf16.h>
#include <math.h>

// Problem constants
#define NTOK 25088      // 8*56*56
#define HW_  3136
#define HH   56
#define WW   56
#define CCH  256
#define NGRP 16
#define NPTS 9
#define HIDN 1024
#define NOFFM 432       // merged off(288)+mask(144) row width
#define TPB  4          // tokens per dcn block

typedef __attribute__((ext_vector_type(8))) __bf16 bf16x8;
typedef __attribute__((ext_vector_type(4))) __bf16 bf16x4;
typedef __attribute__((ext_vector_type(4))) float  f32x4;

static __device__ __forceinline__ void gl_lds16(const void* g, void* l) {
    __builtin_amdgcn_global_load_lds((const __attribute__((address_space(1))) void*)g,
                                     (__attribute__((address_space(3))) void*)l, 16, 0, 0);
}

// tanh-form GELU: max |err| vs exact erf-gelu ~3e-4 (amplified ~5e-4 through fc2)
static __device__ __forceinline__ float gelu_fast(float v) {
    float z = 0.7978845608028654f * (v + 0.044715f * v * v * v);
    float t = 1.0f - 2.0f / (__expf(2.0f * z) + 1.0f);
    return 0.5f * v * (1.0f + t);
}

// ---------------- all weight f32->bf16 converts in one kernel ----------------
__global__ __launch_bounds__(256)
void cvt_all_kernel(const float* __restrict__ inp_w, const float* __restrict__ out_w,
                    const float* __restrict__ off_w, const float* __restrict__ mask_w,
                    const float* __restrict__ fc1_w, const float* __restrict__ fc2_w,
                    __bf16* wib, __bf16* wob, __bf16* wcat, __bf16* w1b, __bf16* w2b) {
    int i = blockIdx.x * 256 + threadIdx.x;
    const float* s; __bf16* d; int off;
    if (i < 16384)       { s = inp_w;  d = wib;          off = i; }
    else if (i < 32768)  { s = out_w;  d = wob;          off = i - 16384; }
    else if (i < 51200)  { s = off_w;  d = wcat;         off = i - 32768; }
    else if (i < 60416)  { s = mask_w; d = wcat + 73728; off = i - 51200; }
    else if (i < 125952) { s = fc1_w;  d = w1b;          off = i - 60416; }
    else if (i < 191488) { s = fc2_w;  d = w2b;          off = i - 125952; }
    else return;
    float4 v = ((const float4*)s)[off];
    bf16x4 o = {(__bf16)v.x, (__bf16)v.y, (__bf16)v.z, (__bf16)v.w};
    ((bf16x4*)d)[off] = o;
}

__global__ void biascat_kernel(const float* __restrict__ ob, const float* __restrict__ mb,
                               float* __restrict__ bc) {
    int i = threadIdx.x;
    if (i < 288) bc[i] = ob[i];
    else if (i < 432) bc[i] = mb[i - 288];
}

// ---------------- LayerNorm: one wave per token (C=256), bf16 out ----------------
__global__ __launch_bounds__(256)
void ln_kernel(const float* __restrict__ x, const float* __restrict__ g,
               const float* __restrict__ b, __bf16* __restrict__ outb, int ntok) {
    int gid  = blockIdx.x * 256 + threadIdx.x;
    int t    = gid >> 6;
    int lane = threadIdx.x & 63;
    if (t >= ntok) return;
    float4 v = ((const float4*)(x + (size_t)t * CCH))[lane];
    float s = v.x + v.y + v.z + v.w;
#pragma unroll
    for (int o = 1; o < 64; o <<= 1) s += __shfl_xor(s, o);
    float mu = s * 0.00390625f;
    float dx = v.x - mu, dy = v.y - mu, dz = v.z - mu, dw = v.w - mu;
    float q = dx * dx + dy * dy + dz * dz + dw * dw;
#pragma unroll
    for (int o = 1; o < 64; o <<= 1) q += __shfl_xor(q, o);
    float rstd = rsqrtf(q * 0.00390625f + 1e-6f);
    float4 gg = ((const float4*)g)[lane];
    float4 bb = ((const float4*)b)[lane];
    bf16x4 ob = {(__bf16)(dx * rstd * gg.x + bb.x), (__bf16)(dy * rstd * gg.y + bb.y),
                 (__bf16)(dz * rstd * gg.z + bb.z), (__bf16)(dw * rstd * gg.w + bb.w)};
    ((bf16x4*)(outb + (size_t)t * CCH))[lane] = ob;
}

// ---------------- depthwise 3x3 conv (pad 1), bf16 in, thread = token x 4 channels ----------------
__global__ __launch_bounds__(256)
void dwconv_kernel(const __bf16* __restrict__ ln, const float* __restrict__ wt,
                   const float* __restrict__ bias, __bf16* __restrict__ out) {
    int gid = blockIdx.x * 256 + threadIdx.x;
    int t = gid >> 6;
    int cq = gid & 63;
    if (t >= NTOK) return;
    int n = t / HW_, hw = t % HW_;
    int h = hw / WW, w0 = hw % WW;
    float4 a = ((const float4*)bias)[cq];
    const bf16x4* l4 = (const bf16x4*)ln;
    const float4* w4 = (const float4*)wt;
#pragma unroll
    for (int ky = 0; ky < 3; ++ky) {
        int y = h + ky - 1;
        if (y < 0 || y >= HH) continue;
#pragma unroll
        for (int kx = 0; kx < 3; ++kx) {
            int x = w0 + kx - 1;
            if (x < 0 || x >= WW) continue;
            bf16x4 v = l4[(size_t)(n * HW_ + y * WW + x) * 64 + cq];
            float4 ww = w4[(ky * 3 + kx) * 64 + cq];
            a.x += (float)v[0] * ww.x; a.y += (float)v[1] * ww.y;
            a.z += (float)v[2] * ww.z; a.w += (float)v[3] * ww.w;
        }
    }
    bf16x4 ob = {(__bf16)a.x, (__bf16)a.y, (__bf16)a.z, (__bf16)a.w};
    ((bf16x4*)out)[(size_t)t * 64 + cq] = ob;
}

// ---------------- GEMM: out[M,N] = A[M,K] @ W[N,K]^T + bias ----------------
// m97 structure + 16B-granule XOR swizzle on LDS staging/reads,
// B-fragment remap (rows wc+4*mrow+ni) -> lane owns 4 consecutive cols -> float4 epilogue.
// EPI 1: f32 out = gemm+bias+resid ; EPI 2: bf16 out = gelu(gemm+bias) ; EPI 3: bf16 out = gemm+bias
template <int EPI>
__global__ __launch_bounds__(256, 4)
void gemm_kernel(const __bf16* __restrict__ A, const __bf16* __restrict__ W,
                 const float* __restrict__ bias, const float* __restrict__ resid,
                 float* __restrict__ outf, __bf16* __restrict__ outb,
                 const int Ndim, const int Kdim) {
    __shared__ __align__(16) __bf16 Alds[128 * 32];
    __shared__ __align__(16) __bf16 Blds[128 * 32];

    const int tid  = threadIdx.x;
    const int w    = tid >> 6;
    const int lane = tid & 63;
    const int m0   = blockIdx.x * 128;
    const int n0   = blockIdx.y * 128;
    const int wr   = (w >> 1) * 64;
    const int wc   = (w & 1) * 64;

    f32x4 acc[4][4];
#pragma unroll
    for (int i = 0; i < 4; ++i)
#pragma unroll
        for (int j = 0; j < 4; ++j) acc[i][j] = (f32x4){0.f, 0.f, 0.f, 0.f};

    const int c0 = (w * 2 + 0) * 64 + lane;
    const int c1 = (w * 2 + 1) * 64 + lane;
    const int ar0 = c0 >> 2, ab0 = ((c0 & 3) ^ ((c0 >> 4) & 3)) * 16;
    const int ar1 = c1 >> 2, ab1 = ((c1 & 3) ^ ((c1 >> 4) & 3)) * 16;
    int br0 = n0 + ar0; if (br0 > Ndim - 1) br0 = Ndim - 1;
    int br1 = n0 + ar1; if (br1 > Ndim - 1) br1 = Ndim - 1;

    const char* Ab = (const char*)A;
    const char* Wb = (const char*)W;
    char* AL = (char*)Alds;
    char* BL = (char*)Blds;
    const size_t rb = (size_t)Kdim * 2;

    const int mrow = lane & 15;
    const int q    = lane >> 4;
    const int kA   = ((q ^ (mrow >> 2)) & 3) * 16;
    const int kB   = ((q ^ mrow) & 3) * 16;

    for (int k0 = 0; k0 < Kdim; k0 += 32) {
        const size_t kb = (size_t)k0 * 2;
        gl_lds16(Ab + (size_t)(m0 + ar0) * rb + kb + ab0, AL + (w * 2 + 0) * 1024);
        gl_lds16(Ab + (size_t)(m0 + ar1) * rb + kb + ab1, AL + (w * 2 + 1) * 1024);
        gl_lds16(Wb + (size_t)br0 * rb + kb + ab0,        BL + (w * 2 + 0) * 1024);
        gl_lds16(Wb + (size_t)br1 * rb + kb + ab1,        BL + (w * 2 + 1) * 1024);
        __syncthreads();
        bf16x8 af[4], bfr[4];
#pragma unroll
        for (int i = 0; i < 4; ++i)
            af[i] = *(const bf16x8*)(AL + (wr + i * 16 + mrow) * 64 + kA);
#pragma unroll
        for (int i = 0; i < 4; ++i)
            bfr[i] = *(const bf16x8*)(BL + (wc + 4 * mrow + i) * 64 + kB);
#pragma unroll
        for (int mi = 0; mi < 4; ++mi)
#pragma unroll
            for (int ni = 0; ni < 4; ++ni)
                acc[mi][ni] = __builtin_amdgcn_mfma_f32_16x16x32_bf16(af[mi], bfr[ni], acc[mi][ni], 0, 0, 0);
        __syncthreads();
    }

    const int coll = lane & 15;
    const int rowh = (lane >> 4) * 4;
    const int col0 = n0 + wc + 4 * coll;
    if (col0 < Ndim) {
        const float4 bv = *(const float4*)(bias + col0);
#pragma unroll
        for (int mi = 0; mi < 4; ++mi) {
#pragma unroll
            for (int j = 0; j < 4; ++j) {
                const int row = m0 + wr + mi * 16 + rowh + j;
                const size_t idx = (size_t)row * (size_t)Ndim + col0;
                float4 v = make_float4(acc[mi][0][j] + bv.x, acc[mi][1][j] + bv.y,
                                       acc[mi][2][j] + bv.z, acc[mi][3][j] + bv.w);
                if (EPI == 1) {
                    const float4 r = *(const float4*)(resid + idx);
                    v.x += r.x; v.y += r.y; v.z += r.z; v.w += r.w;
                    *(float4*)(outf + idx) = v;
                } else if (EPI == 2) {
                    bf16x4 ob = {(__bf16)gelu_fast(v.x), (__bf16)gelu_fast(v.y),
                                 (__bf16)gelu_fast(v.z), (__bf16)gelu_fast(v.w)};
                    *(bf16x4*)(outb + idx) = ob;
                } else {
                    bf16x4 ob = {(__bf16)v.x, (__bf16)v.y, (__bf16)v.z, (__bf16)v.w};
                    *(bf16x4*)(outb + idx) = ob;
                }
            }
        }
    }
}

// ---------------- DCNv3 core: block = 4 tokens; bf16 xp/om; XCD-chunked swizzle ----------------
__global__ __launch_bounds__(256)
void dcn_kernel(const __bf16* __restrict__ xp, const __bf16* __restrict__ om,
                __bf16* __restrict__ out) {
    __shared__ float  raw[TPB][NOFFM];            // offsets[0,288) + mask[288,432), f32
    __shared__ int4   sidx[NPTS][TPB * NGRP];     // 4 clamped tap indices (y*W+x)
    __shared__ float4 swt[NPTS][TPB * NGRP];      // 4 bilinear weights * softmax(mask)
    const int tid = threadIdx.x;
    // XCD-chunked bijective swizzle: 6272 blocks = 8 XCDs x 784; XCD k -> image k
    const int bid = blockIdx.x;
    const int b   = (bid & 7) * 784 + (bid >> 3);
    const int t0  = b * TPB;

    // A: stage om rows (bf16 -> f32), 1728 elems = 216 threads x bf16x8
    if (tid < (TPB * NOFFM) / 8) {
        bf16x8 v = *(const bf16x8*)(om + (size_t)t0 * NOFFM + tid * 8);
        float* d = &raw[0][0] + tid * 8;
#pragma unroll
        for (int k = 0; k < 8; ++k) d[k] = (float)v[k];
    }
    __syncthreads();

    // B: per-(token,group) softmax over 9 points, premultiplied in place
    if (tid < TPB * NGRP) {
        const int lt = tid >> 4, g = tid & 15;
        float* m = &raw[lt][288 + g * 9];
        float mx = m[0];
#pragma unroll
        for (int p = 1; p < 9; ++p) mx = fmaxf(mx, m[p]);
        float s = 0.f, e[9];
#pragma unroll
        for (int p = 0; p < 9; ++p) { e[p] = __expf(m[p] - mx); s += e[p]; }
        const float inv = 1.f / s;
#pragma unroll
        for (int p = 0; p < 9; ++p) m[p] = e[p] * inv;
    }
    __syncthreads();

    // C: tap precompute, one entry per (lt, g, p)
    for (int e = tid; e < TPB * NGRP * NPTS; e += 256) {
        const int lt = e / 144, r = e % 144, g = r / 9, p = r % 9;
        const int t  = t0 + lt;
        const int hw = t % HW_;
        const int h = hw / WW, w0 = hw % WW;
        const float offx = raw[lt][g * 18 + p * 2 + 0];
        const float offy = raw[lt][g * 18 + p * 2 + 1];
        const float pm   = raw[lt][288 + g * 9 + p];
        const int kx = p / 3, ky = p % 3;          // w-major point order
        const float fx = (float)(w0 + kx - 1) + offx;
        const float fy = (float)(h  + ky - 1) + offy;
        const float x0f = floorf(fx), y0f = floorf(fy);
        const float wx = fx - x0f, wy = fy - y0f;
        const int x0 = (int)x0f, y0 = (int)y0f;
        const bool xv0 = (unsigned)x0 < WW, xv1 = (unsigned)(x0 + 1) < WW;
        const bool yv0 = (unsigned)y0 < HH, yv1 = (unsigned)(y0 + 1) < HH;
        const int xc0 = min(max(x0, 0), WW - 1), xc1 = min(max(x0 + 1, 0), WW - 1);
        const int yc0 = min(max(y0, 0), HH - 1), yc1 = min(max(y0 + 1, 0), HH - 1);
        const int tg = lt * 16 + g;
        sidx[p][tg] = make_int4(yc0 * WW + xc0, yc0 * WW + xc1, yc1 * WW + xc0, yc1 * WW + xc1);
        swt[p][tg]  = make_float4((xv0 && yv0) ? (1.f - wx) * (1.f - wy) * pm : 0.f,
                                  (xv1 && yv0) ? wx * (1.f - wy) * pm : 0.f,
                                  (xv0 && yv1) ? (1.f - wx) * wy * pm : 0.f,
                                  (xv1 && yv1) ? wx * wy * pm : 0.f);
    }
    __syncthreads();

    // D: gather (bf16 taps). thread = (lt, g, cq); channel base = lane*4
    const int lt = tid >> 6, lane = tid & 63;
    const int g = lane >> 2;
    const int t = t0 + lt;
    const int n = t / HW_;
    const int tg = lt * 16 + g;
    const __bf16* base = xp + (size_t)n * HW_ * CCH + lane * 4;
    f32x4 acc = {0.f, 0.f, 0.f, 0.f};
#pragma unroll
    for (int p = 0; p < NPTS; ++p) {
        const int4   id = sidx[p][tg];
        const float4 wv = swt[p][tg];
        bf16x4 v0 = *(const bf16x4*)(base + (size_t)id.x * CCH);
        bf16x4 v1 = *(const bf16x4*)(base + (size_t)id.y * CCH);
        bf16x4 v2 = *(const bf16x4*)(base + (size_t)id.z * CCH);
        bf16x4 v3 = *(const bf16x4*)(base + (size_t)id.w * CCH);
#pragma unroll
        for (int k = 0; k < 4; ++k)
            acc[k] += wv.x * (float)v0[k] + wv.y * (float)v1[k]
                    + wv.z * (float)v2[k] + wv.w * (float)v3[k];
    }
    bf16x4 ob = {(__bf16)acc[0], (__bf16)acc[1], (__bf16)acc[2], (__bf16)acc[3]};
    ((bf16x4*)out)[(size_t)t * 64 + lane] = ob;
}

// ---------------- launch ----------------
extern "C" void kernel_launch(void* const* d_in, const int* in_sizes, int n_in,
                              void* d_out, int out_size, void* d_ws, size_t ws_size,
                              hipStream_t stream) {
    const float* x      = (const float*)d_in[0];
    const float* ln1_g  = (const float*)d_in[1];
    const float* ln1_b  = (const float*)d_in[2];
    const float* dw_w   = (const float*)d_in[3];
    const float* dw_b   = (const float*)d_in[4];
    const float* off_w  = (const float*)d_in[5];
    const float* off_b  = (const float*)d_in[6];
    const float* mask_w = (const float*)d_in[7];
    const float* mask_b = (const float*)d_in[8];
    const float* inp_w  = (const float*)d_in[9];
    const float* inp_b  = (const float*)d_in[10];
    const float* out_w  = (const float*)d_in[11];
    const float* out_b  = (const float*)d_in[12];
    const float* ln2_g  = (const float*)d_in[13];
    const float* ln2_b  = (const float*)d_in[14];
    const float* fc1_w  = (const float*)d_in[15];
    const float* fc1_b  = (const float*)d_in[16];
    const float* fc2_w  = (const float*)d_in[17];
    const float* fc2_b  = (const float*)d_in[18];
    float* out = (float*)d_out;

    char* ws = (char*)d_ws;
    size_t o = 0;
    auto alloc = [&](size_t bytes) { size_t r = o; o += (bytes + 255) & ~(size_t)255; return r; };
    float*  yf    = (float*)(ws + alloc((size_t)NTOK * CCH * 4));     // y buffer
    __bf16* x1b   = (__bf16*)(ws + alloc((size_t)NTOK * CCH * 2));    // reused as l2b
    __bf16* lnb   = (__bf16*)(ws + alloc((size_t)NTOK * CCH * 2));    // reused as dcnb; h1b starts here
    __bf16* xpb   = (__bf16*)(ws + alloc((size_t)NTOK * CCH * 2));    // bf16 input-proj
    __bf16* offmb = (__bf16*)(ws + alloc((size_t)NTOK * NOFFM * 2));  // bf16 merged off+mask
    alloc(4 * 1024 * 1024);                                           // pad so h1 (51.4MB) fits at lnb
    __bf16* wib   = (__bf16*)(ws + alloc((size_t)65536 * 2));
    __bf16* wob   = (__bf16*)(ws + alloc((size_t)65536 * 2));
    __bf16* wcat  = (__bf16*)(ws + alloc((size_t)110592 * 2));        // off(288)+mask(144) x 256
    __bf16* w1b   = (__bf16*)(ws + alloc((size_t)262144 * 2));
    __bf16* w2b   = (__bf16*)(ws + alloc((size_t)262144 * 2));
    float*  bcat  = (float*)(ws + alloc((size_t)432 * 4));
    if (ws_size < o) return;

    __bf16* dcnb = lnb;                 // dead after out-proj
    __bf16* l2b  = x1b;                 // live into fc1
    __bf16* h1b  = lnb;                 // 51.4MB over lnb+xpb+offmb+pad (all dead by fc1)

    cvt_all_kernel<<<748, 256, 0, stream>>>(inp_w, out_w, off_w, mask_w, fc1_w, fc2_w,
                                            wib, wob, wcat, w1b, w2b);
    biascat_kernel<<<1, 512, 0, stream>>>(off_b, mask_b, bcat);

    ln_kernel<<<NTOK / 4, 256, 0, stream>>>(x, ln1_g, ln1_b, lnb, NTOK);
    dwconv_kernel<<<NTOK / 4, 256, 0, stream>>>(lnb, dw_w, dw_b, x1b);
    // merged offset+mask projection -> bf16
    gemm_kernel<3><<<dim3(196, 4), 256, 0, stream>>>(x1b, wcat, bcat, nullptr, nullptr, offmb, NOFFM, 256);
    // input projection -> bf16
    gemm_kernel<3><<<dim3(196, 2), 256, 0, stream>>>(lnb, wib, inp_b, nullptr, nullptr, xpb, 256, 256);
    // deformable sampling (XCD-chunked swizzle inside)
    dcn_kernel<<<NTOK / TPB, 256, 0, stream>>>(xpb, offmb, dcnb);
    // output projection + residual(x) -> y (f32)
    gemm_kernel<1><<<dim3(196, 2), 256, 0, stream>>>(dcnb, wob, out_b, x, yf, nullptr, 256, 256);
    // LN2 -> bf16
    ln_kernel<<<NTOK / 4, 256, 0, stream>>>(yf, ln2_g, ln2_b, l2b, NTOK);
    // fc1 + GELU -> bf16
    gemm_kernel<2><<<dim3(196, 8), 256, 0, stream>>>(l2b, w1b, fc1_b, nullptr, nullptr, h1b, 1024, 256);
    // fc2 + residual(y) -> out (f32)
    gemm_kernel<1><<<dim3(196, 2), 256, 0, stream>>>(h1b, w2b, fc2_b, yf, out, nullptr, 256, 1024);
}

// Round 7
// 193.683 us; speedup vs baseline: 1.4004x; 1.0148x over previous
//
#include <hip/hip_runtime.h>
#include <hip/hip_bf16.h>
#include <math.h>

// Problem constants
#define NTOK 25088      // 8*56*56
#define HW_  3136
#define HH   56
#define WW   56
#define CCH  256
#define NGRP 16
#define NPTS 9
#define HIDN 1024
#define NOFFM 432       // merged off(288)+mask(144) row width
#define TPB  4          // tokens per dcn block

typedef __attribute__((ext_vector_type(8))) __bf16 bf16x8;
typedef __attribute__((ext_vector_type(4))) __bf16 bf16x4;
typedef __attribute__((ext_vector_type(4))) float  f32x4;

static __device__ __forceinline__ void gl_lds16(const void* g, void* l) {
    __builtin_amdgcn_global_load_lds((const __attribute__((address_space(1))) void*)g,
                                     (__attribute__((address_space(3))) void*)l, 16, 0, 0);
}

// tanh-form GELU: max |err| vs exact erf-gelu ~3e-4 (amplified ~5e-4 through fc2)
static __device__ __forceinline__ float gelu_fast(float v) {
    float z = 0.7978845608028654f * (v + 0.044715f * v * v * v);
    float t = 1.0f - 2.0f / (__expf(2.0f * z) + 1.0f);
    return 0.5f * v * (1.0f + t);
}

// ---------------- all weight f32->bf16 converts in one kernel ----------------
__global__ __launch_bounds__(256)
void cvt_all_kernel(const float* __restrict__ inp_w, const float* __restrict__ out_w,
                    const float* __restrict__ off_w, const float* __restrict__ mask_w,
                    const float* __restrict__ fc1_w, const float* __restrict__ fc2_w,
                    __bf16* wib, __bf16* wob, __bf16* wcat, __bf16* w1b, __bf16* w2b) {
    int i = blockIdx.x * 256 + threadIdx.x;
    const float* s; __bf16* d; int off;
    if (i < 16384)       { s = inp_w;  d = wib;          off = i; }
    else if (i < 32768)  { s = out_w;  d = wob;          off = i - 16384; }
    else if (i < 51200)  { s = off_w;  d = wcat;         off = i - 32768; }
    else if (i < 60416)  { s = mask_w; d = wcat + 73728; off = i - 51200; }
    else if (i < 125952) { s = fc1_w;  d = w1b;          off = i - 60416; }
    else if (i < 191488) { s = fc2_w;  d = w2b;          off = i - 125952; }
    else return;
    float4 v = ((const float4*)s)[off];
    bf16x4 o = {(__bf16)v.x, (__bf16)v.y, (__bf16)v.z, (__bf16)v.w};
    ((bf16x4*)d)[off] = o;
}

__global__ void biascat_kernel(const float* __restrict__ ob, const float* __restrict__ mb,
                               float* __restrict__ bc) {
    int i = threadIdx.x;
    if (i < 288) bc[i] = ob[i];
    else if (i < 432) bc[i] = mb[i - 288];
}

// ---------------- LayerNorm: one wave per token (C=256), bf16 out ----------------
__global__ __launch_bounds__(256)
void ln_kernel(const float* __restrict__ x, const float* __restrict__ g,
               const float* __restrict__ b, __bf16* __restrict__ outb, int ntok) {
    int gid  = blockIdx.x * 256 + threadIdx.x;
    int t    = gid >> 6;
    int lane = threadIdx.x & 63;
    if (t >= ntok) return;
    float4 v = ((const float4*)(x + (size_t)t * CCH))[lane];
    float s = v.x + v.y + v.z + v.w;
#pragma unroll
    for (int o = 1; o < 64; o <<= 1) s += __shfl_xor(s, o);
    float mu = s * 0.00390625f;
    float dx = v.x - mu, dy = v.y - mu, dz = v.z - mu, dw = v.w - mu;
    float q = dx * dx + dy * dy + dz * dz + dw * dw;
#pragma unroll
    for (int o = 1; o < 64; o <<= 1) q += __shfl_xor(q, o);
    float rstd = rsqrtf(q * 0.00390625f + 1e-6f);
    float4 gg = ((const float4*)g)[lane];
    float4 bb = ((const float4*)b)[lane];
    bf16x4 ob = {(__bf16)(dx * rstd * gg.x + bb.x), (__bf16)(dy * rstd * gg.y + bb.y),
                 (__bf16)(dz * rstd * gg.z + bb.z), (__bf16)(dw * rstd * gg.w + bb.w)};
    ((bf16x4*)(outb + (size_t)t * CCH))[lane] = ob;
}

// ---------------- depthwise 3x3 conv (pad 1), bf16 in, thread = token x 4 channels ----------------
__global__ __launch_bounds__(256)
void dwconv_kernel(const __bf16* __restrict__ ln, const float* __restrict__ wt,
                   const float* __restrict__ bias, __bf16* __restrict__ out) {
    int gid = blockIdx.x * 256 + threadIdx.x;
    int t = gid >> 6;
    int cq = gid & 63;
    if (t >= NTOK) return;
    int n = t / HW_, hw = t % HW_;
    int h = hw / WW, w0 = hw % WW;
    float4 a = ((const float4*)bias)[cq];
    const bf16x4* l4 = (const bf16x4*)ln;
    const float4* w4 = (const float4*)wt;
#pragma unroll
    for (int ky = 0; ky < 3; ++ky) {
        int y = h + ky - 1;
        if (y < 0 || y >= HH) continue;
#pragma unroll
        for (int kx = 0; kx < 3; ++kx) {
            int x = w0 + kx - 1;
            if (x < 0 || x >= WW) continue;
            bf16x4 v = l4[(size_t)(n * HW_ + y * WW + x) * 64 + cq];
            float4 ww = w4[(ky * 3 + kx) * 64 + cq];
            a.x += (float)v[0] * ww.x; a.y += (float)v[1] * ww.y;
            a.z += (float)v[2] * ww.z; a.w += (float)v[3] * ww.w;
        }
    }
    bf16x4 ob = {(__bf16)a.x, (__bf16)a.y, (__bf16)a.z, (__bf16)a.w};
    ((bf16x4*)out)[(size_t)t * 64 + cq] = ob;
}

// ---------------- GEMM: out[M,N] = A[M,K] @ W[N,K]^T + bias ----------------
// 2-phase double-buffered K-loop (stage t+1 before compute t; one barrier/iter).
// A: linear LDS rows, 16B-slot XOR s=(row>>2)&3  -> 2-way conflict (free).
// B: row-PERMUTED LDS (row r holds W-row 64*(r>>6)+4*(r&15)+((r>>4)&3)), slot XOR
//    s=(r>>1)&3 -> read rows wc+16i+mrow, 2-way conflict; lane owns 4 consecutive
//    output cols -> float4/bf16x4 epilogue.
// EPI 1: f32 out = gemm+bias+resid ; EPI 2: bf16 out = gelu(gemm+bias) ; EPI 3: bf16 out = gemm+bias
template <int EPI>
__global__ __launch_bounds__(256, 4)
void gemm_kernel(const __bf16* __restrict__ A, const __bf16* __restrict__ W,
                 const float* __restrict__ bias, const float* __restrict__ resid,
                 float* __restrict__ outf, __bf16* __restrict__ outb,
                 const int Ndim, const int Kdim) {
    __shared__ __align__(16) __bf16 Alds[2][128 * 32];
    __shared__ __align__(16) __bf16 Blds[2][128 * 32];

    const int tid  = threadIdx.x;
    const int w    = tid >> 6;
    const int lane = tid & 63;
    const int m0   = blockIdx.x * 128;
    const int n0   = blockIdx.y * 128;
    const int wr   = (w >> 1) * 64;
    const int wc   = (w & 1) * 64;

    f32x4 acc[4][4];
#pragma unroll
    for (int i = 0; i < 4; ++i)
#pragma unroll
        for (int j = 0; j < 4; ++j) acc[i][j] = (f32x4){0.f, 0.f, 0.f, 0.f};

    // staging positions: 512 x 16B per 128x32 tile; this thread covers p0, p1
    const int p0 = (w * 2 + 0) * 64 + lane;
    const int p1 = p0 + 64;
    // A source: row = p>>2 (linear), global chunk = (p&3) ^ ((p>>4)&3)
    const int ar0 = p0 >> 2, ab0 = ((p0 & 3) ^ ((p0 >> 4) & 3)) * 16;
    const int ar1 = p1 >> 2, ab1 = ((p1 & 3) ^ ((p1 >> 4) & 3)) * 16;
    // B source: LDS row r = p>>2 holds W-row R(r); global chunk = (p&3) ^ ((p>>3)&3)
    const int br0 = p0 >> 2, br1 = p1 >> 2;
    int bR0 = n0 + ((br0 >> 6) << 6) + 4 * (br0 & 15) + ((br0 >> 4) & 3);
    int bR1 = n0 + ((br1 >> 6) << 6) + 4 * (br1 & 15) + ((br1 >> 4) & 3);
    if (bR0 > Ndim - 1) bR0 = Ndim - 1;
    if (bR1 > Ndim - 1) bR1 = Ndim - 1;
    const int bb0 = ((p0 & 3) ^ ((p0 >> 3) & 3)) * 16;
    const int bb1 = ((p1 & 3) ^ ((p1 >> 3) & 3)) * 16;

    const char* Ab = (const char*)A;
    const char* Wb = (const char*)W;
    char* AL = (char*)&Alds[0][0];
    char* BL = (char*)&Blds[0][0];
    const size_t rb = (size_t)Kdim * 2;
    const size_t sA0 = (size_t)(m0 + ar0) * rb + ab0;
    const size_t sA1 = (size_t)(m0 + ar1) * rb + ab1;
    const size_t sB0 = (size_t)bR0 * rb + bb0;
    const size_t sB1 = (size_t)bR1 * rb + bb1;
    const int d0 = (w * 2 + 0) * 1024;
    const int d1 = (w * 2 + 1) * 1024;

#define STAGE(BUF, KB)                                        \
    do {                                                      \
        gl_lds16(Ab + sA0 + (KB), AL + (BUF) * 8192 + d0);    \
        gl_lds16(Ab + sA1 + (KB), AL + (BUF) * 8192 + d1);    \
        gl_lds16(Wb + sB0 + (KB), BL + (BUF) * 8192 + d0);    \
        gl_lds16(Wb + sB1 + (KB), BL + (BUF) * 8192 + d1);    \
    } while (0)

    const int mrow = lane & 15;
    const int q    = lane >> 4;
    const int kA   = ((q ^ (mrow >> 2)) & 3) * 16;
    const int kB   = ((q ^ (mrow >> 1)) & 3) * 16;

    int cur = 0;
    STAGE(0, 0);
    __syncthreads();
    for (int k0 = 0; k0 < Kdim; k0 += 32) {
        const bool more = (k0 + 32 < Kdim);
        if (more) STAGE(cur ^ 1, (size_t)(k0 + 32) * 2);
        bf16x8 af[4], bfr[4];
#pragma unroll
        for (int i = 0; i < 4; ++i)
            af[i] = *(const bf16x8*)(AL + cur * 8192 + (wr + i * 16 + mrow) * 64 + kA);
#pragma unroll
        for (int i = 0; i < 4; ++i)
            bfr[i] = *(const bf16x8*)(BL + cur * 8192 + (wc + i * 16 + mrow) * 64 + kB);
#pragma unroll
        for (int mi = 0; mi < 4; ++mi)
#pragma unroll
            for (int ni = 0; ni < 4; ++ni)
                acc[mi][ni] = __builtin_amdgcn_mfma_f32_16x16x32_bf16(af[mi], bfr[ni], acc[mi][ni], 0, 0, 0);
        if (more) {
            __syncthreads();   // drains vmcnt(0): next buffer staged; cur reads done
            cur ^= 1;
        }
    }
#undef STAGE

    const int coll = lane & 15;
    const int rowh = (lane >> 4) * 4;
    const int col0 = n0 + wc + 4 * coll;
    if (col0 < Ndim) {
        const float4 bv = *(const float4*)(bias + col0);
#pragma unroll
        for (int mi = 0; mi < 4; ++mi) {
#pragma unroll
            for (int j = 0; j < 4; ++j) {
                const int row = m0 + wr + mi * 16 + rowh + j;
                const size_t idx = (size_t)row * (size_t)Ndim + col0;
                float4 v = make_float4(acc[mi][0][j] + bv.x, acc[mi][1][j] + bv.y,
                                       acc[mi][2][j] + bv.z, acc[mi][3][j] + bv.w);
                if (EPI == 1) {
                    const float4 r = *(const float4*)(resid + idx);
                    v.x += r.x; v.y += r.y; v.z += r.z; v.w += r.w;
                    *(float4*)(outf + idx) = v;
                } else if (EPI == 2) {
                    bf16x4 ob = {(__bf16)gelu_fast(v.x), (__bf16)gelu_fast(v.y),
                                 (__bf16)gelu_fast(v.z), (__bf16)gelu_fast(v.w)};
                    *(bf16x4*)(outb + idx) = ob;
                } else {
                    bf16x4 ob = {(__bf16)v.x, (__bf16)v.y, (__bf16)v.z, (__bf16)v.w};
                    *(bf16x4*)(outb + idx) = ob;
                }
            }
        }
    }
}

// ---------------- DCNv3 core: block = 4 tokens; bf16 xp/om; XCD-chunked swizzle ----------------
__global__ __launch_bounds__(256)
void dcn_kernel(const __bf16* __restrict__ xp, const __bf16* __restrict__ om,
                __bf16* __restrict__ out) {
    __shared__ float  raw[TPB][NOFFM];            // offsets[0,288) + mask[288,432), f32
    __shared__ int4   sidx[NPTS][TPB * NGRP];     // 4 clamped tap indices (y*W+x)
    __shared__ float4 swt[NPTS][TPB * NGRP];      // 4 bilinear weights * softmax(mask)
    const int tid = threadIdx.x;
    // XCD-chunked bijective swizzle: 6272 blocks = 8 XCDs x 784; XCD k -> image k
    const int bid = blockIdx.x;
    const int b   = (bid & 7) * 784 + (bid >> 3);
    const int t0  = b * TPB;

    // A: stage om rows (bf16 -> f32), 1728 elems = 216 threads x bf16x8
    if (tid < (TPB * NOFFM) / 8) {
        bf16x8 v = *(const bf16x8*)(om + (size_t)t0 * NOFFM + tid * 8);
        float* d = &raw[0][0] + tid * 8;
#pragma unroll
        for (int k = 0; k < 8; ++k) d[k] = (float)v[k];
    }
    __syncthreads();

    // B: per-(token,group) softmax over 9 points, premultiplied in place
    if (tid < TPB * NGRP) {
        const int lt = tid >> 4, g = tid & 15;
        float* m = &raw[lt][288 + g * 9];
        float mx = m[0];
#pragma unroll
        for (int p = 1; p < 9; ++p) mx = fmaxf(mx, m[p]);
        float s = 0.f, e[9];
#pragma unroll
        for (int p = 0; p < 9; ++p) { e[p] = __expf(m[p] - mx); s += e[p]; }
        const float inv = 1.f / s;
#pragma unroll
        for (int p = 0; p < 9; ++p) m[p] = e[p] * inv;
    }
    __syncthreads();

    // C: tap precompute, one entry per (lt, g, p)
    for (int e = tid; e < TPB * NGRP * NPTS; e += 256) {
        const int lt = e / 144, r = e % 144, g = r / 9, p = r % 9;
        const int t  = t0 + lt;
        const int hw = t % HW_;
        const int h = hw / WW, w0 = hw % WW;
        const float offx = raw[lt][g * 18 + p * 2 + 0];
        const float offy = raw[lt][g * 18 + p * 2 + 1];
        const float pm   = raw[lt][288 + g * 9 + p];
        const int kx = p / 3, ky = p % 3;          // w-major point order
        const float fx = (float)(w0 + kx - 1) + offx;
        const float fy = (float)(h  + ky - 1) + offy;
        const float x0f = floorf(fx), y0f = floorf(fy);
        const float wx = fx - x0f, wy = fy - y0f;
        const int x0 = (int)x0f, y0 = (int)y0f;
        const bool xv0 = (unsigned)x0 < WW, xv1 = (unsigned)(x0 + 1) < WW;
        const bool yv0 = (unsigned)y0 < HH, yv1 = (unsigned)(y0 + 1) < HH;
        const int xc0 = min(max(x0, 0), WW - 1), xc1 = min(max(x0 + 1, 0), WW - 1);
        const int yc0 = min(max(y0, 0), HH - 1), yc1 = min(max(y0 + 1, 0), HH - 1);
        const int tg = lt * 16 + g;
        sidx[p][tg] = make_int4(yc0 * WW + xc0, yc0 * WW + xc1, yc1 * WW + xc0, yc1 * WW + xc1);
        swt[p][tg]  = make_float4((xv0 && yv0) ? (1.f - wx) * (1.f - wy) * pm : 0.f,
                                  (xv1 && yv0) ? wx * (1.f - wy) * pm : 0.f,
                                  (xv0 && yv1) ? (1.f - wx) * wy * pm : 0.f,
                                  (xv1 && yv1) ? wx * wy * pm : 0.f);
    }
    __syncthreads();

    // D: gather (bf16 taps). thread = (lt, g, cq); channel base = lane*4
    const int lt = tid >> 6, lane = tid & 63;
    const int g = lane >> 2;
    const int t = t0 + lt;
    const int n = t / HW_;
    const int tg = lt * 16 + g;
    const __bf16* base = xp + (size_t)n * HW_ * CCH + lane * 4;
    f32x4 acc = {0.f, 0.f, 0.f, 0.f};
#pragma unroll
    for (int p = 0; p < NPTS; ++p) {
        const int4   id = sidx[p][tg];
        const float4 wv = swt[p][tg];
        bf16x4 v0 = *(const bf16x4*)(base + (size_t)id.x * CCH);
        bf16x4 v1 = *(const bf16x4*)(base + (size_t)id.y * CCH);
        bf16x4 v2 = *(const bf16x4*)(base + (size_t)id.z * CCH);
        bf16x4 v3 = *(const bf16x4*)(base + (size_t)id.w * CCH);
#pragma unroll
        for (int k = 0; k < 4; ++k)
            acc[k] += wv.x * (float)v0[k] + wv.y * (float)v1[k]
                    + wv.z * (float)v2[k] + wv.w * (float)v3[k];
    }
    bf16x4 ob = {(__bf16)acc[0], (__bf16)acc[1], (__bf16)acc[2], (__bf16)acc[3]};
    ((bf16x4*)out)[(size_t)t * 64 + lane] = ob;
}

// ---------------- launch ----------------
extern "C" void kernel_launch(void* const* d_in, const int* in_sizes, int n_in,
                              void* d_out, int out_size, void* d_ws, size_t ws_size,
                              hipStream_t stream) {
    const float* x      = (const float*)d_in[0];
    const float* ln1_g  = (const float*)d_in[1];
    const float* ln1_b  = (const float*)d_in[2];
    const float* dw_w   = (const float*)d_in[3];
    const float* dw_b   = (const float*)d_in[4];
    const float* off_w  = (const float*)d_in[5];
    const float* off_b  = (const float*)d_in[6];
    const float* mask_w = (const float*)d_in[7];
    const float* mask_b = (const float*)d_in[8];
    const float* inp_w  = (const float*)d_in[9];
    const float* inp_b  = (const float*)d_in[10];
    const float* out_w  = (const float*)d_in[11];
    const float* out_b  = (const float*)d_in[12];
    const float* ln2_g  = (const float*)d_in[13];
    const float* ln2_b  = (const float*)d_in[14];
    const float* fc1_w  = (const float*)d_in[15];
    const float* fc1_b  = (const float*)d_in[16];
    const float* fc2_w  = (const float*)d_in[17];
    const float* fc2_b  = (const float*)d_in[18];
    float* out = (float*)d_out;

    char* ws = (char*)d_ws;
    size_t o = 0;
    auto alloc = [&](size_t bytes) { size_t r = o; o += (bytes + 255) & ~(size_t)255; return r; };
    float*  yf    = (float*)(ws + alloc((size_t)NTOK * CCH * 4));     // y buffer
    __bf16* x1b   = (__bf16*)(ws + alloc((size_t)NTOK * CCH * 2));    // reused as l2b
    __bf16* lnb   = (__bf16*)(ws + alloc((size_t)NTOK * CCH * 2));    // reused as dcnb; h1b starts here
    __bf16* xpb   = (__bf16*)(ws + alloc((size_t)NTOK * CCH * 2));    // bf16 input-proj
    __bf16* offmb = (__bf16*)(ws + alloc((size_t)NTOK * NOFFM * 2));  // bf16 merged off+mask
    alloc(4 * 1024 * 1024);                                           // pad so h1 (51.4MB) fits at lnb
    __bf16* wib   = (__bf16*)(ws + alloc((size_t)65536 * 2));
    __bf16* wob   = (__bf16*)(ws + alloc((size_t)65536 * 2));
    __bf16* wcat  = (__bf16*)(ws + alloc((size_t)110592 * 2));        // off(288)+mask(144) x 256
    __bf16* w1b   = (__bf16*)(ws + alloc((size_t)262144 * 2));
    __bf16* w2b   = (__bf16*)(ws + alloc((size_t)262144 * 2));
    float*  bcat  = (float*)(ws + alloc((size_t)432 * 4));
    if (ws_size < o) return;

    __bf16* dcnb = lnb;                 // dead after out-proj
    __bf16* l2b  = x1b;                 // live into fc1
    __bf16* h1b  = lnb;                 // 51.4MB over lnb+xpb+offmb+pad (all dead by fc1)

    cvt_all_kernel<<<748, 256, 0, stream>>>(inp_w, out_w, off_w, mask_w, fc1_w, fc2_w,
                                            wib, wob, wcat, w1b, w2b);
    biascat_kernel<<<1, 512, 0, stream>>>(off_b, mask_b, bcat);

    ln_kernel<<<NTOK / 4, 256, 0, stream>>>(x, ln1_g, ln1_b, lnb, NTOK);
    dwconv_kernel<<<NTOK / 4, 256, 0, stream>>>(lnb, dw_w, dw_b, x1b);
    // merged offset+mask projection -> bf16
    gemm_kernel<3><<<dim3(196, 4), 256, 0, stream>>>(x1b, wcat, bcat, nullptr, nullptr, offmb, NOFFM, 256);
    // input projection -> bf16
    gemm_kernel<3><<<dim3(196, 2), 256, 0, stream>>>(lnb, wib, inp_b, nullptr, nullptr, xpb, 256, 256);
    // deformable sampling (XCD-chunked swizzle inside)
    dcn_kernel<<<NTOK / TPB, 256, 0, stream>>>(xpb, offmb, dcnb);
    // output projection + residual(x) -> y (f32)
    gemm_kernel<1><<<dim3(196, 2), 256, 0, stream>>>(dcnb, wob, out_b, x, yf, nullptr, 256, 256);
    // LN2 -> bf16
    ln_kernel<<<NTOK / 4, 256, 0, stream>>>(yf, ln2_g, ln2_b, l2b, NTOK);
    // fc1 + GELU -> bf16
    gemm_kernel<2><<<dim3(196, 8), 256, 0, stream>>>(l2b, w1b, fc1_b, nullptr, nullptr, h1b, 1024, 256);
    // fc2 + residual(y) -> out (f32)
    gemm_kernel<1><<<dim3(196, 2), 256, 0, stream>>>(h1b, w2b, fc2_b, yf, out, nullptr, 256, 1024);
}

// Round 8
// 183.025 us; speedup vs baseline: 1.4819x; 1.0582x over previous
//
#include <hip/hip_runtime.h>
#include <hip/hip_bf16.h>
#include <math.h>

// Problem constants
#define NTOK 25088      // 8*56*56
#define HW_  3136
#define HH   56
#define WW   56
#define CCH  256
#define NGRP 16
#define NPTS 9
#define HIDN 1024
#define NOFFM 432       // merged off(288)+mask(144) row width
#define TPB  4          // tokens per dcn block

typedef __attribute__((ext_vector_type(8))) __bf16 bf16x8;
typedef __attribute__((ext_vector_type(4))) __bf16 bf16x4;
typedef __attribute__((ext_vector_type(4))) float  f32x4;

static __device__ __forceinline__ void gl_lds16(const void* g, void* l) {
    __builtin_amdgcn_global_load_lds((const __attribute__((address_space(1))) void*)g,
                                     (__attribute__((address_space(3))) void*)l, 16, 0, 0);
}

// tanh-form GELU via identity 0.5v(1+tanh z) = v * sigmoid(2z); fast rcp.
static __device__ __forceinline__ float gelu_fast(float v) {
    float v2 = v * v;
    float z2 = fmaf(0.0713548163f * v, v2, 1.5957691216f * v);   // 2z
    float r  = __builtin_amdgcn_rcpf(__expf(-z2) + 1.0f);        // sigmoid(2z)
    return v * r;
}

// ---------------- weight f32->bf16 converts + bias concat, one kernel ----------------
__global__ __launch_bounds__(256)
void cvt_all_kernel(const float* __restrict__ inp_w, const float* __restrict__ out_w,
                    const float* __restrict__ off_w, const float* __restrict__ mask_w,
                    const float* __restrict__ fc1_w, const float* __restrict__ fc2_w,
                    const float* __restrict__ off_b, const float* __restrict__ mask_b,
                    __bf16* wib, __bf16* wob, __bf16* wcat, __bf16* w1b, __bf16* w2b,
                    float* bcat) {
    int i = blockIdx.x * 256 + threadIdx.x;
    if (i >= 191488) {
        int j = i - 191488;
        if (j < 432) bcat[j] = (j < 288) ? off_b[j] : mask_b[j - 288];
        return;
    }
    const float* s; __bf16* d; int off;
    if (i < 16384)       { s = inp_w;  d = wib;          off = i; }
    else if (i < 32768)  { s = out_w;  d = wob;          off = i - 16384; }
    else if (i < 51200)  { s = off_w;  d = wcat;         off = i - 32768; }
    else if (i < 60416)  { s = mask_w; d = wcat + 73728; off = i - 51200; }
    else if (i < 125952) { s = fc1_w;  d = w1b;          off = i - 60416; }
    else                 { s = fc2_w;  d = w2b;          off = i - 125952; }
    float4 v = ((const float4*)s)[off];
    bf16x4 o = {(__bf16)v.x, (__bf16)v.y, (__bf16)v.z, (__bf16)v.w};
    ((bf16x4*)d)[off] = o;
}

// ---------------- LayerNorm: one wave per token (C=256), bf16 out ----------------
__global__ __launch_bounds__(256)
void ln_kernel(const float* __restrict__ x, const float* __restrict__ g,
               const float* __restrict__ b, __bf16* __restrict__ outb, int ntok) {
    int gid  = blockIdx.x * 256 + threadIdx.x;
    int t    = gid >> 6;
    int lane = threadIdx.x & 63;
    if (t >= ntok) return;
    float4 v = ((const float4*)(x + (size_t)t * CCH))[lane];
    float s = v.x + v.y + v.z + v.w;
#pragma unroll
    for (int o = 1; o < 64; o <<= 1) s += __shfl_xor(s, o);
    float mu = s * 0.00390625f;
    float dx = v.x - mu, dy = v.y - mu, dz = v.z - mu, dw = v.w - mu;
    float q = dx * dx + dy * dy + dz * dz + dw * dw;
#pragma unroll
    for (int o = 1; o < 64; o <<= 1) q += __shfl_xor(q, o);
    float rstd = rsqrtf(q * 0.00390625f + 1e-6f);
    float4 gg = ((const float4*)g)[lane];
    float4 bb = ((const float4*)b)[lane];
    bf16x4 ob = {(__bf16)(dx * rstd * gg.x + bb.x), (__bf16)(dy * rstd * gg.y + bb.y),
                 (__bf16)(dz * rstd * gg.z + bb.z), (__bf16)(dw * rstd * gg.w + bb.w)};
    ((bf16x4*)(outb + (size_t)t * CCH))[lane] = ob;
}

// ---------------- depthwise 3x3 conv (pad 1), bf16 in, thread = token x 4 channels ----------------
__global__ __launch_bounds__(256)
void dwconv_kernel(const __bf16* __restrict__ ln, const float* __restrict__ wt,
                   const float* __restrict__ bias, __bf16* __restrict__ out) {
    int gid = blockIdx.x * 256 + threadIdx.x;
    int t = gid >> 6;
    int cq = gid & 63;
    if (t >= NTOK) return;
    int n = t / HW_, hw = t % HW_;
    int h = hw / WW, w0 = hw % WW;
    float4 a = ((const float4*)bias)[cq];
    const bf16x4* l4 = (const bf16x4*)ln;
    const float4* w4 = (const float4*)wt;
#pragma unroll
    for (int ky = 0; ky < 3; ++ky) {
        int y = h + ky - 1;
        if (y < 0 || y >= HH) continue;
#pragma unroll
        for (int kx = 0; kx < 3; ++kx) {
            int x = w0 + kx - 1;
            if (x < 0 || x >= WW) continue;
            bf16x4 v = l4[(size_t)(n * HW_ + y * WW + x) * 64 + cq];
            float4 ww = w4[(ky * 3 + kx) * 64 + cq];
            a.x += (float)v[0] * ww.x; a.y += (float)v[1] * ww.y;
            a.z += (float)v[2] * ww.z; a.w += (float)v[3] * ww.w;
        }
    }
    bf16x4 ob = {(__bf16)a.x, (__bf16)a.y, (__bf16)a.z, (__bf16)a.w};
    ((bf16x4*)out)[(size_t)t * 64 + cq] = ob;
}

// ---------------- GEMM: out[M,N] = A[M,K] @ W[N,K]^T + bias ----------------
// BM=64 x BN=128 tile, 256 threads (4 waves, wave = 32x64), double-buffered BK=32.
// A: linear LDS rows, slot XOR s=(row>>2)&3. B: row-permuted LDS (row r holds W-row
// 64*(r>>6)+4*(r&15)+((r>>4)&3)), slot XOR s=(r>>1)&3 -> lane owns 4 consecutive
// output cols -> float4/bf16x4 epilogue. XCD-chunked grid remap (gridDim.x % 8 == 0).
// EPI 1: f32 = gemm+bias+resid ; EPI 2: bf16 = gelu(gemm+bias) ; EPI 3: bf16 = gemm+bias
template <int EPI>
__global__ __launch_bounds__(256, 6)
void gemm_kernel(const __bf16* __restrict__ A, const __bf16* __restrict__ W,
                 const float* __restrict__ bias, const float* __restrict__ resid,
                 float* __restrict__ outf, __bf16* __restrict__ outb,
                 const int Ndim, const int Kdim, const int NB) {
    __shared__ __align__(16) __bf16 Alds[2][64 * 32];
    __shared__ __align__(16) __bf16 Blds[2][128 * 32];

    const int tid  = threadIdx.x;
    const int w    = tid >> 6;
    const int lane = tid & 63;
    // XCD-chunked bijective remap; n-fastest within a chunk -> per-XCD A-panel reuse in L2
    const int chunk = gridDim.x >> 3;
    const int lin   = (blockIdx.x & 7) * chunk + (blockIdx.x >> 3);
    const int m0 = (lin / NB) * 64;
    const int n0 = (lin % NB) * 128;
    const int wr = (w >> 1) * 32;
    const int wc = (w & 1) * 64;

    f32x4 acc[2][4];
#pragma unroll
    for (int i = 0; i < 2; ++i)
#pragma unroll
        for (int j = 0; j < 4; ++j) acc[i][j] = (f32x4){0.f, 0.f, 0.f, 0.f};

    // staging: A tile = 256 x 16B chunks (1/thread), B tile = 512 (2/thread)
    const int pA   = tid;
    const int arow = pA >> 2, abyte = ((pA & 3) ^ ((pA >> 4) & 3)) * 16;
    const int pB1  = tid + 256;
    const int br0  = tid >> 2, br1 = pB1 >> 2;
    int bR0 = n0 + ((br0 >> 6) << 6) + 4 * (br0 & 15) + ((br0 >> 4) & 3);
    int bR1 = n0 + ((br1 >> 6) << 6) + 4 * (br1 & 15) + ((br1 >> 4) & 3);
    if (bR0 > Ndim - 1) bR0 = Ndim - 1;
    if (bR1 > Ndim - 1) bR1 = Ndim - 1;
    const int bb0 = ((tid & 3) ^ ((tid >> 3) & 3)) * 16;
    const int bb1 = ((pB1 & 3) ^ ((pB1 >> 3) & 3)) * 16;

    const char* Ab = (const char*)A;
    const char* Wb = (const char*)W;
    char* AL = (char*)&Alds[0][0];
    char* BL = (char*)&Blds[0][0];
    const size_t rb  = (size_t)Kdim * 2;
    const size_t sA  = (size_t)(m0 + arow) * rb + abyte;
    const size_t sB0 = (size_t)bR0 * rb + bb0;
    const size_t sB1 = (size_t)bR1 * rb + bb1;
    const int dof = w * 1024;   // wave-uniform LDS dest base (HW adds lane*16)

#define STAGE(BUF, KB)                                                 \
    do {                                                               \
        gl_lds16(Ab + sA  + (KB), AL + (BUF) * 4096 + dof);            \
        gl_lds16(Wb + sB0 + (KB), BL + (BUF) * 8192 + dof);            \
        gl_lds16(Wb + sB1 + (KB), BL + (BUF) * 8192 + 4096 + dof);     \
    } while (0)

    const int mrow = lane & 15;
    const int q    = lane >> 4;
    const int kA   = ((q ^ (mrow >> 2)) & 3) * 16;
    const int kB   = ((q ^ (mrow >> 1)) & 3) * 16;

    int cur = 0;
    STAGE(0, 0);
    __syncthreads();
    for (int k0 = 0; k0 < Kdim; k0 += 32) {
        const bool more = (k0 + 32 < Kdim);
        if (more) STAGE(cur ^ 1, (size_t)(k0 + 32) * 2);
        bf16x8 af[2], bfr[4];
#pragma unroll
        for (int i = 0; i < 2; ++i)
            af[i] = *(const bf16x8*)(AL + cur * 4096 + (wr + i * 16 + mrow) * 64 + kA);
#pragma unroll
        for (int i = 0; i < 4; ++i)
            bfr[i] = *(const bf16x8*)(BL + cur * 8192 + (wc + i * 16 + mrow) * 64 + kB);
#pragma unroll
        for (int mi = 0; mi < 2; ++mi)
#pragma unroll
            for (int ni = 0; ni < 4; ++ni)
                acc[mi][ni] = __builtin_amdgcn_mfma_f32_16x16x32_bf16(af[mi], bfr[ni], acc[mi][ni], 0, 0, 0);
        if (more) {
            __syncthreads();   // drains vmcnt(0): next buffer staged; cur reads done
            cur ^= 1;
        }
    }
#undef STAGE

    const int coll = lane & 15;
    const int rowh = (lane >> 4) * 4;
    const int col0 = n0 + wc + 4 * coll;
    if (col0 < Ndim) {
        const float4 bv = *(const float4*)(bias + col0);
#pragma unroll
        for (int mi = 0; mi < 2; ++mi) {
#pragma unroll
            for (int j = 0; j < 4; ++j) {
                const int row = m0 + wr + mi * 16 + rowh + j;
                const size_t idx = (size_t)row * (size_t)Ndim + col0;
                float4 v = make_float4(acc[mi][0][j] + bv.x, acc[mi][1][j] + bv.y,
                                       acc[mi][2][j] + bv.z, acc[mi][3][j] + bv.w);
                if (EPI == 1) {
                    const float4 r = *(const float4*)(resid + idx);
                    v.x += r.x; v.y += r.y; v.z += r.z; v.w += r.w;
                    *(float4*)(outf + idx) = v;
                } else if (EPI == 2) {
                    bf16x4 ob = {(__bf16)gelu_fast(v.x), (__bf16)gelu_fast(v.y),
                                 (__bf16)gelu_fast(v.z), (__bf16)gelu_fast(v.w)};
                    *(bf16x4*)(outb + idx) = ob;
                } else {
                    bf16x4 ob = {(__bf16)v.x, (__bf16)v.y, (__bf16)v.z, (__bf16)v.w};
                    *(bf16x4*)(outb + idx) = ob;
                }
            }
        }
    }
}

// ---------------- DCNv3 core: block = 4 tokens; bf16 xp/om; XCD-chunked swizzle ----------------
__global__ __launch_bounds__(256)
void dcn_kernel(const __bf16* __restrict__ xp, const __bf16* __restrict__ om,
                __bf16* __restrict__ out) {
    __shared__ float  raw[TPB][NOFFM];            // offsets[0,288) + mask[288,432), f32
    __shared__ int4   sidx[NPTS][TPB * NGRP];     // 4 clamped tap indices (y*W+x)
    __shared__ float4 swt[NPTS][TPB * NGRP];      // 4 bilinear weights * softmax(mask)
    const int tid = threadIdx.x;
    // XCD-chunked bijective swizzle: 6272 blocks = 8 XCDs x 784; XCD k -> image k
    const int bid = blockIdx.x;
    const int b   = (bid & 7) * 784 + (bid >> 3);
    const int t0  = b * TPB;

    if (tid < (TPB * NOFFM) / 8) {
        bf16x8 v = *(const bf16x8*)(om + (size_t)t0 * NOFFM + tid * 8);
        float* d = &raw[0][0] + tid * 8;
#pragma unroll
        for (int k = 0; k < 8; ++k) d[k] = (float)v[k];
    }
    __syncthreads();

    if (tid < TPB * NGRP) {
        const int lt = tid >> 4, g = tid & 15;
        float* m = &raw[lt][288 + g * 9];
        float mx = m[0];
#pragma unroll
        for (int p = 1; p < 9; ++p) mx = fmaxf(mx, m[p]);
        float s = 0.f, e[9];
#pragma unroll
        for (int p = 0; p < 9; ++p) { e[p] = __expf(m[p] - mx); s += e[p]; }
        const float inv = 1.f / s;
#pragma unroll
        for (int p = 0; p < 9; ++p) m[p] = e[p] * inv;
    }
    __syncthreads();

    for (int e = tid; e < TPB * NGRP * NPTS; e += 256) {
        const int lt = e / 144, r = e % 144, g = r / 9, p = r % 9;
        const int t  = t0 + lt;
        const int hw = t % HW_;
        const int h = hw / WW, w0 = hw % WW;
        const float offx = raw[lt][g * 18 + p * 2 + 0];
        const float offy = raw[lt][g * 18 + p * 2 + 1];
        const float pm   = raw[lt][288 + g * 9 + p];
        const int kx = p / 3, ky = p % 3;          // w-major point order
        const float fx = (float)(w0 + kx - 1) + offx;
        const float fy = (float)(h  + ky - 1) + offy;
        const float x0f = floorf(fx), y0f = floorf(fy);
        const float wx = fx - x0f, wy = fy - y0f;
        const int x0 = (int)x0f, y0 = (int)y0f;
        const bool xv0 = (unsigned)x0 < WW, xv1 = (unsigned)(x0 + 1) < WW;
        const bool yv0 = (unsigned)y0 < HH, yv1 = (unsigned)(y0 + 1) < HH;
        const int xc0 = min(max(x0, 0), WW - 1), xc1 = min(max(x0 + 1, 0), WW - 1);
        const int yc0 = min(max(y0, 0), HH - 1), yc1 = min(max(y0 + 1, 0), HH - 1);
        const int tg = lt * 16 + g;
        sidx[p][tg] = make_int4(yc0 * WW + xc0, yc0 * WW + xc1, yc1 * WW + xc0, yc1 * WW + xc1);
        swt[p][tg]  = make_float4((xv0 && yv0) ? (1.f - wx) * (1.f - wy) * pm : 0.f,
                                  (xv1 && yv0) ? wx * (1.f - wy) * pm : 0.f,
                                  (xv0 && yv1) ? (1.f - wx) * wy * pm : 0.f,
                                  (xv1 && yv1) ? wx * wy * pm : 0.f);
    }
    __syncthreads();

    const int lt = tid >> 6, lane = tid & 63;
    const int g = lane >> 2;
    const int t = t0 + lt;
    const int n = t / HW_;
    const int tg = lt * 16 + g;
    const __bf16* base = xp + (size_t)n * HW_ * CCH + lane * 4;
    f32x4 acc = {0.f, 0.f, 0.f, 0.f};
#pragma unroll
    for (int p = 0; p < NPTS; ++p) {
        const int4   id = sidx[p][tg];
        const float4 wv = swt[p][tg];
        bf16x4 v0 = *(const bf16x4*)(base + (size_t)id.x * CCH);
        bf16x4 v1 = *(const bf16x4*)(base + (size_t)id.y * CCH);
        bf16x4 v2 = *(const bf16x4*)(base + (size_t)id.z * CCH);
        bf16x4 v3 = *(const bf16x4*)(base + (size_t)id.w * CCH);
#pragma unroll
        for (int k = 0; k < 4; ++k)
            acc[k] += wv.x * (float)v0[k] + wv.y * (float)v1[k]
                    + wv.z * (float)v2[k] + wv.w * (float)v3[k];
    }
    bf16x4 ob = {(__bf16)acc[0], (__bf16)acc[1], (__bf16)acc[2], (__bf16)acc[3]};
    ((bf16x4*)out)[(size_t)t * 64 + lane] = ob;
}

// ---------------- launch ----------------
extern "C" void kernel_launch(void* const* d_in, const int* in_sizes, int n_in,
                              void* d_out, int out_size, void* d_ws, size_t ws_size,
                              hipStream_t stream) {
    const float* x      = (const float*)d_in[0];
    const float* ln1_g  = (const float*)d_in[1];
    const float* ln1_b  = (const float*)d_in[2];
    const float* dw_w   = (const float*)d_in[3];
    const float* dw_b   = (const float*)d_in[4];
    const float* off_w  = (const float*)d_in[5];
    const float* off_b  = (const float*)d_in[6];
    const float* mask_w = (const float*)d_in[7];
    const float* mask_b = (const float*)d_in[8];
    const float* inp_w  = (const float*)d_in[9];
    const float* inp_b  = (const float*)d_in[10];
    const float* out_w  = (const float*)d_in[11];
    const float* out_b  = (const float*)d_in[12];
    const float* ln2_g  = (const float*)d_in[13];
    const float* ln2_b  = (const float*)d_in[14];
    const float* fc1_w  = (const float*)d_in[15];
    const float* fc1_b  = (const float*)d_in[16];
    const float* fc2_w  = (const float*)d_in[17];
    const float* fc2_b  = (const float*)d_in[18];
    float* out = (float*)d_out;

    char* ws = (char*)d_ws;
    size_t o = 0;
    auto alloc = [&](size_t bytes) { size_t r = o; o += (bytes + 255) & ~(size_t)255; return r; };
    float*  yf    = (float*)(ws + alloc((size_t)NTOK * CCH * 4));     // y buffer
    __bf16* x1b   = (__bf16*)(ws + alloc((size_t)NTOK * CCH * 2));    // reused as l2b
    __bf16* lnb   = (__bf16*)(ws + alloc((size_t)NTOK * CCH * 2));    // reused as dcnb; h1b starts here
    __bf16* xpb   = (__bf16*)(ws + alloc((size_t)NTOK * CCH * 2));    // bf16 input-proj
    __bf16* offmb = (__bf16*)(ws + alloc((size_t)NTOK * NOFFM * 2));  // bf16 merged off+mask
    alloc(4 * 1024 * 1024);                                           // pad so h1 (51.4MB) fits at lnb
    __bf16* wib   = (__bf16*)(ws + alloc((size_t)65536 * 2));
    __bf16* wob   = (__bf16*)(ws + alloc((size_t)65536 * 2));
    __bf16* wcat  = (__bf16*)(ws + alloc((size_t)110592 * 2));        // off(288)+mask(144) x 256
    __bf16* w1b   = (__bf16*)(ws + alloc((size_t)262144 * 2));
    __bf16* w2b   = (__bf16*)(ws + alloc((size_t)262144 * 2));
    float*  bcat  = (float*)(ws + alloc((size_t)432 * 4));
    if (ws_size < o) return;

    __bf16* dcnb = lnb;                 // dead after out-proj
    __bf16* l2b  = x1b;                 // live into fc1
    __bf16* h1b  = lnb;                 // 51.4MB over lnb+xpb+offmb+pad (all dead by fc1)

    cvt_all_kernel<<<750, 256, 0, stream>>>(inp_w, out_w, off_w, mask_w, fc1_w, fc2_w,
                                            off_b, mask_b, wib, wob, wcat, w1b, w2b, bcat);

    ln_kernel<<<NTOK / 4, 256, 0, stream>>>(x, ln1_g, ln1_b, lnb, NTOK);
    dwconv_kernel<<<NTOK / 4, 256, 0, stream>>>(lnb, dw_w, dw_b, x1b);
    // merged offset+mask projection -> bf16 (M-blocks=392, NB=4)
    gemm_kernel<3><<<392 * 4, 256, 0, stream>>>(x1b, wcat, bcat, nullptr, nullptr, offmb, NOFFM, 256, 4);
    // input projection -> bf16
    gemm_kernel<3><<<392 * 2, 256, 0, stream>>>(lnb, wib, inp_b, nullptr, nullptr, xpb, 256, 256, 2);
    // deformable sampling (XCD-chunked swizzle inside)
    dcn_kernel<<<NTOK / TPB, 256, 0, stream>>>(xpb, offmb, dcnb);
    // output projection + residual(x) -> y (f32)
    gemm_kernel<1><<<392 * 2, 256, 0, stream>>>(dcnb, wob, out_b, x, yf, nullptr, 256, 256, 2);
    // LN2 -> bf16
    ln_kernel<<<NTOK / 4, 256, 0, stream>>>(yf, ln2_g, ln2_b, l2b, NTOK);
    // fc1 + GELU -> bf16
    gemm_kernel<2><<<392 * 8, 256, 0, stream>>>(l2b, w1b, fc1_b, nullptr, nullptr, h1b, 1024, 256, 8);
    // fc2 + residual(y) -> out (f32)
    gemm_kernel<1><<<392 * 2, 256, 0, stream>>>(h1b, w2b, fc2_b, yf, out, nullptr, 256, 1024, 2);
}

// Round 9
// 171.888 us; speedup vs baseline: 1.5779x; 1.0648x over previous
//
#include <hip/hip_runtime.h>
#include <hip/hip_bf16.h>
#include <math.h>

// Problem constants
#define NTOK 25088      // 8*56*56
#define HW_  3136
#define HH   56
#define WW   56
#define CCH  256
#define NGRP 16
#define NPTS 9
#define HIDN 1024
#define NOFFM 432       // merged off(288)+mask(144) row width
#define TPB  8          // tokens per dcn block (thread = token x 8 channels)

typedef __attribute__((ext_vector_type(8))) __bf16 bf16x8;
typedef __attribute__((ext_vector_type(4))) __bf16 bf16x4;
typedef __attribute__((ext_vector_type(4))) float  f32x4;

static __device__ __forceinline__ void gl_lds16(const void* g, void* l) {
    __builtin_amdgcn_global_load_lds((const __attribute__((address_space(1))) void*)g,
                                     (__attribute__((address_space(3))) void*)l, 16, 0, 0);
}

// tanh-form GELU via identity 0.5v(1+tanh z) = v * sigmoid(2z); fast rcp.
static __device__ __forceinline__ float gelu_fast(float v) {
    float v2 = v * v;
    float z2 = fmaf(0.0713548163f * v, v2, 1.5957691216f * v);   // 2z
    float r  = __builtin_amdgcn_rcpf(__expf(-z2) + 1.0f);        // sigmoid(2z)
    return v * r;
}

// ---------------- weight f32->bf16 converts + bias concat, one kernel ----------------
__global__ __launch_bounds__(256)
void cvt_all_kernel(const float* __restrict__ inp_w, const float* __restrict__ out_w,
                    const float* __restrict__ off_w, const float* __restrict__ mask_w,
                    const float* __restrict__ fc1_w, const float* __restrict__ fc2_w,
                    const float* __restrict__ off_b, const float* __restrict__ mask_b,
                    __bf16* wib, __bf16* wob, __bf16* wcat, __bf16* w1b, __bf16* w2b,
                    float* bcat) {
    int i = blockIdx.x * 256 + threadIdx.x;
    if (i >= 191488) {
        int j = i - 191488;
        if (j < 432) bcat[j] = (j < 288) ? off_b[j] : mask_b[j - 288];
        return;
    }
    const float* s; __bf16* d; int off;
    if (i < 16384)       { s = inp_w;  d = wib;          off = i; }
    else if (i < 32768)  { s = out_w;  d = wob;          off = i - 16384; }
    else if (i < 51200)  { s = off_w;  d = wcat;         off = i - 32768; }
    else if (i < 60416)  { s = mask_w; d = wcat + 73728; off = i - 51200; }
    else if (i < 125952) { s = fc1_w;  d = w1b;          off = i - 60416; }
    else                 { s = fc2_w;  d = w2b;          off = i - 125952; }
    float4 v = ((const float4*)s)[off];
    bf16x4 o = {(__bf16)v.x, (__bf16)v.y, (__bf16)v.z, (__bf16)v.w};
    ((bf16x4*)d)[off] = o;
}

// ---------------- LayerNorm: one wave per token (C=256), f32 in, bf16 out ----------------
__global__ __launch_bounds__(256)
void ln_f_kernel(const float* __restrict__ x, const float* __restrict__ g,
                 const float* __restrict__ b, __bf16* __restrict__ outb) {
    int gid  = blockIdx.x * 256 + threadIdx.x;
    int t    = gid >> 6;
    int lane = threadIdx.x & 63;
    if (t >= NTOK) return;
    float4 v = ((const float4*)(x + (size_t)t * CCH))[lane];
    float s = v.x + v.y + v.z + v.w;
#pragma unroll
    for (int o = 1; o < 64; o <<= 1) s += __shfl_xor(s, o);
    float mu = s * 0.00390625f;
    float dx = v.x - mu, dy = v.y - mu, dz = v.z - mu, dw = v.w - mu;
    float q = dx * dx + dy * dy + dz * dz + dw * dw;
#pragma unroll
    for (int o = 1; o < 64; o <<= 1) q += __shfl_xor(q, o);
    float rstd = rsqrtf(q * 0.00390625f + 1e-6f);
    float4 gg = ((const float4*)g)[lane];
    float4 bb = ((const float4*)b)[lane];
    bf16x4 ob = {(__bf16)(dx * rstd * gg.x + bb.x), (__bf16)(dy * rstd * gg.y + bb.y),
                 (__bf16)(dz * rstd * gg.z + bb.z), (__bf16)(dw * rstd * gg.w + bb.w)};
    ((bf16x4*)(outb + (size_t)t * CCH))[lane] = ob;
}

// ---------------- LayerNorm: bf16 in, bf16 out ----------------
__global__ __launch_bounds__(256)
void ln_b_kernel(const __bf16* __restrict__ x, const float* __restrict__ g,
                 const float* __restrict__ b, __bf16* __restrict__ outb) {
    int gid  = blockIdx.x * 256 + threadIdx.x;
    int t    = gid >> 6;
    int lane = threadIdx.x & 63;
    if (t >= NTOK) return;
    bf16x4 vb = ((const bf16x4*)(x + (size_t)t * CCH))[lane];
    float vx = (float)vb[0], vy = (float)vb[1], vz = (float)vb[2], vw = (float)vb[3];
    float s = vx + vy + vz + vw;
#pragma unroll
    for (int o = 1; o < 64; o <<= 1) s += __shfl_xor(s, o);
    float mu = s * 0.00390625f;
    float dx = vx - mu, dy = vy - mu, dz = vz - mu, dw = vw - mu;
    float q = dx * dx + dy * dy + dz * dz + dw * dw;
#pragma unroll
    for (int o = 1; o < 64; o <<= 1) q += __shfl_xor(q, o);
    float rstd = rsqrtf(q * 0.00390625f + 1e-6f);
    float4 gg = ((const float4*)g)[lane];
    float4 bb = ((const float4*)b)[lane];
    bf16x4 ob = {(__bf16)(dx * rstd * gg.x + bb.x), (__bf16)(dy * rstd * gg.y + bb.y),
                 (__bf16)(dz * rstd * gg.z + bb.z), (__bf16)(dw * rstd * gg.w + bb.w)};
    ((bf16x4*)(outb + (size_t)t * CCH))[lane] = ob;
}

// ---------------- depthwise 3x3 conv (pad 1), bf16 in, thread = token x 4 channels ----------------
__global__ __launch_bounds__(256)
void dwconv_kernel(const __bf16* __restrict__ ln, const float* __restrict__ wt,
                   const float* __restrict__ bias, __bf16* __restrict__ out) {
    int gid = blockIdx.x * 256 + threadIdx.x;
    int t = gid >> 6;
    int cq = gid & 63;
    if (t >= NTOK) return;
    int n = t / HW_, hw = t % HW_;
    int h = hw / WW, w0 = hw % WW;
    float4 a = ((const float4*)bias)[cq];
    const bf16x4* l4 = (const bf16x4*)ln;
    const float4* w4 = (const float4*)wt;
#pragma unroll
    for (int ky = 0; ky < 3; ++ky) {
        int y = h + ky - 1;
        if (y < 0 || y >= HH) continue;
#pragma unroll
        for (int kx = 0; kx < 3; ++kx) {
            int x = w0 + kx - 1;
            if (x < 0 || x >= WW) continue;
            bf16x4 v = l4[(size_t)(n * HW_ + y * WW + x) * 64 + cq];
            float4 ww = w4[(ky * 3 + kx) * 64 + cq];
            a.x += (float)v[0] * ww.x; a.y += (float)v[1] * ww.y;
            a.z += (float)v[2] * ww.z; a.w += (float)v[3] * ww.w;
        }
    }
    bf16x4 ob = {(__bf16)a.x, (__bf16)a.y, (__bf16)a.z, (__bf16)a.w};
    ((bf16x4*)out)[(size_t)t * 64 + cq] = ob;
}

// ---------------- GEMM body: out[M,N] = A[M,K] @ W[N,K]^T + bias ----------------
// BM=64 x BN=128, 256 threads (4 waves of 32x64), double-buffered BK=32.
// A: linear LDS rows, slot XOR s=(row>>2)&3. B: row-permuted LDS (row r holds W-row
// 64*(r>>6)+4*(r&15)+((r>>4)&3)), slot XOR s=(r>>1)&3 -> lane owns 4 consecutive
// output cols -> vectorized epilogue.
// EPI 2: bf16 = gelu(gemm+bias) ; EPI 3: bf16 = gemm+bias ;
// EPI 4: bf16 = gemm+bias+resid_f32 ; EPI 5: f32 = gemm+bias+resid_bf16
template <int EPI>
static __device__ __forceinline__ void gemm_body(
        const __bf16* __restrict__ A, const __bf16* __restrict__ W,
        const float* __restrict__ bias, const float* __restrict__ residf,
        const __bf16* __restrict__ residb, float* __restrict__ outf,
        __bf16* __restrict__ outb, const int Ndim, const int Kdim,
        const int NB, const int lin) {
    __shared__ __align__(16) __bf16 Alds[2][64 * 32];
    __shared__ __align__(16) __bf16 Blds[2][128 * 32];

    const int tid  = threadIdx.x;
    const int w    = tid >> 6;
    const int lane = tid & 63;
    const int m0 = (lin / NB) * 64;
    const int n0 = (lin % NB) * 128;
    const int wr = (w >> 1) * 32;
    const int wc = (w & 1) * 64;

    f32x4 acc[2][4];
#pragma unroll
    for (int i = 0; i < 2; ++i)
#pragma unroll
        for (int j = 0; j < 4; ++j) acc[i][j] = (f32x4){0.f, 0.f, 0.f, 0.f};

    // staging: A tile = 256 x 16B chunks (1/thread), B tile = 512 (2/thread)
    const int pA   = tid;
    const int arow = pA >> 2, abyte = ((pA & 3) ^ ((pA >> 4) & 3)) * 16;
    const int pB1  = tid + 256;
    const int br0  = tid >> 2, br1 = pB1 >> 2;
    int bR0 = n0 + ((br0 >> 6) << 6) + 4 * (br0 & 15) + ((br0 >> 4) & 3);
    int bR1 = n0 + ((br1 >> 6) << 6) + 4 * (br1 & 15) + ((br1 >> 4) & 3);
    if (bR0 > Ndim - 1) bR0 = Ndim - 1;
    if (bR1 > Ndim - 1) bR1 = Ndim - 1;
    const int bb0 = ((tid & 3) ^ ((tid >> 3) & 3)) * 16;
    const int bb1 = ((pB1 & 3) ^ ((pB1 >> 3) & 3)) * 16;

    const char* Ab = (const char*)A;
    const char* Wb = (const char*)W;
    char* AL = (char*)&Alds[0][0];
    char* BL = (char*)&Blds[0][0];
    const size_t rb  = (size_t)Kdim * 2;
    const size_t sA  = (size_t)(m0 + arow) * rb + abyte;
    const size_t sB0 = (size_t)bR0 * rb + bb0;
    const size_t sB1 = (size_t)bR1 * rb + bb1;
    const int dof = w * 1024;   // wave-uniform LDS dest base (HW adds lane*16)

#define STAGE(BUF, KB)                                                 \
    do {                                                               \
        gl_lds16(Ab + sA  + (KB), AL + (BUF) * 4096 + dof);            \
        gl_lds16(Wb + sB0 + (KB), BL + (BUF) * 8192 + dof);            \
        gl_lds16(Wb + sB1 + (KB), BL + (BUF) * 8192 + 4096 + dof);     \
    } while (0)

    const int mrow = lane & 15;
    const int q    = lane >> 4;
    const int kA   = ((q ^ (mrow >> 2)) & 3) * 16;
    const int kB   = ((q ^ (mrow >> 1)) & 3) * 16;

    int cur = 0;
    STAGE(0, 0);
    __syncthreads();
    for (int k0 = 0; k0 < Kdim; k0 += 32) {
        const bool more = (k0 + 32 < Kdim);
        if (more) STAGE(cur ^ 1, (size_t)(k0 + 32) * 2);
        bf16x8 af[2], bfr[4];
#pragma unroll
        for (int i = 0; i < 2; ++i)
            af[i] = *(const bf16x8*)(AL + cur * 4096 + (wr + i * 16 + mrow) * 64 + kA);
#pragma unroll
        for (int i = 0; i < 4; ++i)
            bfr[i] = *(const bf16x8*)(BL + cur * 8192 + (wc + i * 16 + mrow) * 64 + kB);
#pragma unroll
        for (int mi = 0; mi < 2; ++mi)
#pragma unroll
            for (int ni = 0; ni < 4; ++ni)
                acc[mi][ni] = __builtin_amdgcn_mfma_f32_16x16x32_bf16(af[mi], bfr[ni], acc[mi][ni], 0, 0, 0);
        if (more) {
            __syncthreads();   // drains vmcnt(0): next buffer staged; cur reads done
            cur ^= 1;
        }
    }
#undef STAGE

    const int coll = lane & 15;
    const int rowh = (lane >> 4) * 4;
    const int col0 = n0 + wc + 4 * coll;
    if (col0 < Ndim) {
        const float4 bv = *(const float4*)(bias + col0);
#pragma unroll
        for (int mi = 0; mi < 2; ++mi) {
#pragma unroll
            for (int j = 0; j < 4; ++j) {
                const int row = m0 + wr + mi * 16 + rowh + j;
                const size_t idx = (size_t)row * (size_t)Ndim + col0;
                float4 v = make_float4(acc[mi][0][j] + bv.x, acc[mi][1][j] + bv.y,
                                       acc[mi][2][j] + bv.z, acc[mi][3][j] + bv.w);
                if (EPI == 2) {
                    bf16x4 ob = {(__bf16)gelu_fast(v.x), (__bf16)gelu_fast(v.y),
                                 (__bf16)gelu_fast(v.z), (__bf16)gelu_fast(v.w)};
                    *(bf16x4*)(outb + idx) = ob;
                } else if (EPI == 3) {
                    bf16x4 ob = {(__bf16)v.x, (__bf16)v.y, (__bf16)v.z, (__bf16)v.w};
                    *(bf16x4*)(outb + idx) = ob;
                } else if (EPI == 4) {
                    const float4 r = *(const float4*)(residf + idx);
                    bf16x4 ob = {(__bf16)(v.x + r.x), (__bf16)(v.y + r.y),
                                 (__bf16)(v.z + r.z), (__bf16)(v.w + r.w)};
                    *(bf16x4*)(outb + idx) = ob;
                } else {   // EPI 5
                    const bf16x4 r = *(const bf16x4*)(residb + idx);
                    v.x += (float)r[0]; v.y += (float)r[1];
                    v.z += (float)r[2]; v.w += (float)r[3];
                    *(float4*)(outf + idx) = v;
                }
            }
        }
    }
}

template <int EPI>
__global__ __launch_bounds__(256, 6)
void gemm_kernel(const __bf16* __restrict__ A, const __bf16* __restrict__ W,
                 const float* __restrict__ bias, const float* __restrict__ residf,
                 const __bf16* __restrict__ residb, float* __restrict__ outf,
                 __bf16* __restrict__ outb, const int Ndim, const int Kdim, const int NB) {
    // XCD-chunked bijective remap (gridDim.x % 8 == 0); n-fastest within chunk
    const int chunk = gridDim.x >> 3;
    const int lin   = (blockIdx.x & 7) * chunk + (blockIdx.x >> 3);
    gemm_body<EPI>(A, W, bias, residf, residb, outf, outb, Ndim, Kdim, NB, lin);
}

// two independent EPI3 projections (offm, inp) fused into one dispatch
__global__ __launch_bounds__(256, 6)
void gemm_dual_kernel(const __bf16* __restrict__ A1, const __bf16* __restrict__ W1,
                      const float* __restrict__ b1, __bf16* __restrict__ o1,
                      const int N1, const int NB1, const int split,
                      const __bf16* __restrict__ A2, const __bf16* __restrict__ W2,
                      const float* __restrict__ b2, __bf16* __restrict__ o2,
                      const int N2, const int NB2) {
    const int chunk = gridDim.x >> 3;
    const int lin   = (blockIdx.x & 7) * chunk + (blockIdx.x >> 3);
    if (lin < split)
        gemm_body<3>(A1, W1, b1, nullptr, nullptr, nullptr, o1, N1, 256, NB1, lin);
    else
        gemm_body<3>(A2, W2, b2, nullptr, nullptr, nullptr, o2, N2, 256, NB2, lin - split);
}

// ---------------- DCNv3 core: block = 8 tokens; thread = token x 8 channels ----------------
__global__ __launch_bounds__(256)
void dcn_kernel(const __bf16* __restrict__ xp, const __bf16* __restrict__ om,
                __bf16* __restrict__ out) {
    __shared__ __align__(16) __bf16 rawb[TPB][NOFFM];   // off[0,288)+mask[288,432) bf16
    __shared__ ushort4 sidx[NPTS][TPB * NGRP];          // 4 clamped tap indices (y*W+x)
    __shared__ float4  swt[NPTS][TPB * NGRP];           // 4 bilinear wts * softmax(mask)
    const int tid = threadIdx.x;
    // XCD-chunked bijective swizzle: 3136 blocks = 8 XCDs x 392; XCD k -> image k
    const int bid = blockIdx.x;
    const int b   = (bid & 7) * 392 + (bid >> 3);
    const int t0  = b * TPB;

    // A: stage om rows (bf16, coalesced): 3456 elems = 432 x bf16x8
    for (int e = tid; e < (TPB * NOFFM) / 8; e += 256)
        *(bf16x8*)(&rawb[0][0] + e * 8) = *(const bf16x8*)(om + (size_t)t0 * NOFFM + e * 8);
    __syncthreads();

    // B: per-(token,group) softmax over 9 points (f32 math, bf16 store)
    if (tid < TPB * NGRP) {
        const int lt = tid >> 4, g = tid & 15;
        __bf16* m = &rawb[lt][288 + g * 9];
        float e[9];
        float mx = -1e30f;
#pragma unroll
        for (int p = 0; p < 9; ++p) { e[p] = (float)m[p]; mx = fmaxf(mx, e[p]); }
        float s = 0.f;
#pragma unroll
        for (int p = 0; p < 9; ++p) { e[p] = __expf(e[p] - mx); s += e[p]; }
        const float inv = 1.f / s;
#pragma unroll
        for (int p = 0; p < 9; ++p) m[p] = (__bf16)(e[p] * inv);
    }
    __syncthreads();

    // C: tap precompute, one entry per (lt, g, p)
    for (int e = tid; e < TPB * NGRP * NPTS; e += 256) {
        const int lt = e / 144, r = e % 144, g = r / 9, p = r % 9;
        const int t  = t0 + lt;
        const int hw = t % HW_;
        const int h = hw / WW, w0 = hw % WW;
        const float offx = (float)rawb[lt][g * 18 + p * 2 + 0];
        const float offy = (float)rawb[lt][g * 18 + p * 2 + 1];
        const float pm   = (float)rawb[lt][288 + g * 9 + p];
        const int kx = p / 3, ky = p % 3;          // w-major point order
        const float fx = (float)(w0 + kx - 1) + offx;
        const float fy = (float)(h  + ky - 1) + offy;
        const float x0f = floorf(fx), y0f = floorf(fy);
        const float wx = fx - x0f, wy = fy - y0f;
        const int x0 = (int)x0f, y0 = (int)y0f;
        const bool xv0 = (unsigned)x0 < WW, xv1 = (unsigned)(x0 + 1) < WW;
        const bool yv0 = (unsigned)y0 < HH, yv1 = (unsigned)(y0 + 1) < HH;
        const int xc0 = min(max(x0, 0), WW - 1), xc1 = min(max(x0 + 1, 0), WW - 1);
        const int yc0 = min(max(y0, 0), HH - 1), yc1 = min(max(y0 + 1, 0), HH - 1);
        const int tg = lt * 16 + g;
        sidx[p][tg] = make_ushort4((unsigned short)(yc0 * WW + xc0),
                                   (unsigned short)(yc0 * WW + xc1),
                                   (unsigned short)(yc1 * WW + xc0),
                                   (unsigned short)(yc1 * WW + xc1));
        swt[p][tg]  = make_float4((xv0 && yv0) ? (1.f - wx) * (1.f - wy) * pm : 0.f,
                                  (xv1 && yv0) ? wx * (1.f - wy) * pm : 0.f,
                                  (xv0 && yv1) ? (1.f - wx) * wy * pm : 0.f,
                                  (xv1 && yv1) ? wx * wy * pm : 0.f);
    }
    __syncthreads();

    // D: gather. thread = (lt = tid>>5, lane32); channel base = lane32*8; g = lane32>>1
    const int lt = tid >> 5, lane = tid & 31;
    const int g = lane >> 1;
    const int t = t0 + lt;
    const int n = t / HW_;
    const int tg = lt * 16 + g;
    const __bf16* base = xp + (size_t)n * HW_ * CCH + lane * 8;
    float acc[8] = {0.f, 0.f, 0.f, 0.f, 0.f, 0.f, 0.f, 0.f};
#pragma unroll
    for (int p = 0; p < NPTS; ++p) {
        const ushort4 id = sidx[p][tg];
        const float4  wv = swt[p][tg];
        bf16x8 v0 = *(const bf16x8*)(base + (size_t)id.x * CCH);
        bf16x8 v1 = *(const bf16x8*)(base + (size_t)id.y * CCH);
        bf16x8 v2 = *(const bf16x8*)(base + (size_t)id.z * CCH);
        bf16x8 v3 = *(const bf16x8*)(base + (size_t)id.w * CCH);
#pragma unroll
        for (int k = 0; k < 8; ++k)
            acc[k] += wv.x * (float)v0[k] + wv.y * (float)v1[k]
                    + wv.z * (float)v2[k] + wv.w * (float)v3[k];
    }
    bf16x8 ob;
#pragma unroll
    for (int k = 0; k < 8; ++k) ob[k] = (__bf16)acc[k];
    *(bf16x8*)(out + (size_t)t * CCH + lane * 8) = ob;
}

// ---------------- launch ----------------
extern "C" void kernel_launch(void* const* d_in, const int* in_sizes, int n_in,
                              void* d_out, int out_size, void* d_ws, size_t ws_size,
                              hipStream_t stream) {
    const float* x      = (const float*)d_in[0];
    const float* ln1_g  = (const float*)d_in[1];
    const float* ln1_b  = (const float*)d_in[2];
    const float* dw_w   = (const float*)d_in[3];
    const float* dw_b   = (const float*)d_in[4];
    const float* off_w  = (const float*)d_in[5];
    const float* off_b  = (const float*)d_in[6];
    const float* mask_w = (const float*)d_in[7];
    const float* mask_b = (const float*)d_in[8];
    const float* inp_w  = (const float*)d_in[9];
    const float* inp_b  = (const float*)d_in[10];
    const float* out_w  = (const float*)d_in[11];
    const float* out_b  = (const float*)d_in[12];
    const float* ln2_g  = (const float*)d_in[13];
    const float* ln2_b  = (const float*)d_in[14];
    const float* fc1_w  = (const float*)d_in[15];
    const float* fc1_b  = (const float*)d_in[16];
    const float* fc2_w  = (const float*)d_in[17];
    const float* fc2_b  = (const float*)d_in[18];
    float* out = (float*)d_out;

    char* ws = (char*)d_ws;
    size_t o = 0;
    auto alloc = [&](size_t bytes) { size_t r = o; o += (bytes + 255) & ~(size_t)255; return r; };
    __bf16* yb    = (__bf16*)(ws + alloc((size_t)NTOK * CCH * 2));    // y residual, bf16
    __bf16* x1b   = (__bf16*)(ws + alloc((size_t)NTOK * CCH * 2));    // reused as l2b
    __bf16* lnb   = (__bf16*)(ws + alloc((size_t)NTOK * CCH * 2));    // reused as dcnb; h1b starts here
    __bf16* xpb   = (__bf16*)(ws + alloc((size_t)NTOK * CCH * 2));    // bf16 input-proj
    __bf16* offmb = (__bf16*)(ws + alloc((size_t)NTOK * NOFFM * 2));  // bf16 merged off+mask
    alloc(6 * 1024 * 1024);                                           // pad so h1 (51.4MB) fits at lnb
    __bf16* wib   = (__bf16*)(ws + alloc((size_t)65536 * 2));
    __bf16* wob   = (__bf16*)(ws + alloc((size_t)65536 * 2));
    __bf16* wcat  = (__bf16*)(ws + alloc((size_t)110592 * 2));        // off(288)+mask(144) x 256
    __bf16* w1b   = (__bf16*)(ws + alloc((size_t)262144 * 2));
    __bf16* w2b   = (__bf16*)(ws + alloc((size_t)262144 * 2));
    float*  bcat  = (float*)(ws + alloc((size_t)432 * 4));
    if (ws_size < o) return;

    __bf16* dcnb = lnb;                 // dead after out-proj
    __bf16* l2b  = x1b;                 // live into fc1
    __bf16* h1b  = lnb;                 // 51.4MB over lnb+xpb+offmb+pad (all dead by fc1)

    cvt_all_kernel<<<750, 256, 0, stream>>>(inp_w, out_w, off_w, mask_w, fc1_w, fc2_w,
                                            off_b, mask_b, wib, wob, wcat, w1b, w2b, bcat);

    ln_f_kernel<<<NTOK / 4, 256, 0, stream>>>(x, ln1_g, ln1_b, lnb);
    dwconv_kernel<<<NTOK / 4, 256, 0, stream>>>(lnb, dw_w, dw_b, x1b);
    // offm (x1b @ wcat, N=432, NB=4) + inp (lnb @ wib, N=256, NB=2) in one dispatch
    gemm_dual_kernel<<<392 * 4 + 392 * 2, 256, 0, stream>>>(
        x1b, wcat, bcat, offmb, NOFFM, 4, 392 * 4,
        lnb, wib, inp_b, xpb, 256, 2);
    // deformable sampling (XCD-chunked swizzle inside)
    dcn_kernel<<<NTOK / TPB, 256, 0, stream>>>(xpb, offmb, dcnb);
    // output projection + residual(x f32) -> y bf16
    gemm_kernel<4><<<392 * 2, 256, 0, stream>>>(dcnb, wob, out_b, x, nullptr, nullptr, yb, 256, 256, 2);
    // LN2 (bf16 in) -> bf16
    ln_b_kernel<<<NTOK / 4, 256, 0, stream>>>(yb, ln2_g, ln2_b, l2b);
    // fc1 + GELU -> bf16
    gemm_kernel<2><<<392 * 8, 256, 0, stream>>>(l2b, w1b, fc1_b, nullptr, nullptr, nullptr, h1b, 1024, 256, 8);
    // fc2 + residual(y bf16) -> out f32
    gemm_kernel<5><<<392 * 2, 256, 0, stream>>>(h1b, w2b, fc2_b, nullptr, yb, out, nullptr, 256, 1024, 2);
}